// Round 16
// baseline (2843.961 us; speedup 1.0000x reference)
//
#include <hip/hip_runtime.h>
#include <hip/hip_bf16.h>
#include <stdint.h>

// Decoder: 2-layer LSTM + Luong attention. input_feed=0 => attention deferred
// post-loop. R16: persistent recurrence; h streams go DIRECT to VGPR via
// batched volatile-asm global_load_dwordx4 (8 in flight, drained inside the
// batch -> compiler cannot serialize, no pending-register hazard). LDS holds
// only weights (padded rows) + sG. Everything else identical to R15/R12.

typedef __bf16 bf16_t;
typedef __bf16 bf16x8 __attribute__((ext_vector_type(8)));
typedef __bf16 bf16x4 __attribute__((ext_vector_type(4)));
typedef float f32x4 __attribute__((ext_vector_type(4)));

#define AS1 __attribute__((address_space(1)))
#define AS3 __attribute__((address_space(3)))

__device__ __forceinline__ void gll16(const bf16_t* g, bf16_t* l) {
  __builtin_amdgcn_global_load_lds((const AS1 void*)g, (AS3 void*)l, 16, 0, 0);
}

__device__ __forceinline__ float sigm(float x){ return 1.f/(1.f+expf(-x)); }

#define MFMA16(acc, a, b) acc = __builtin_amdgcn_mfma_f32_16x16x32_bf16(a, b, acc, 0,0,0)

// system write-through coherent store (sc1 REQUIRED for cross-XCD visibility)
__device__ __forceinline__ void stg_sc(bf16_t* p, bf16_t v){
  uint32_t w = (uint32_t)__builtin_bit_cast(uint16_t, v);
  asm volatile("global_store_short %0, %1, off sc0 sc1" :: "v"(p), "v"(w) : "memory");
}

// ordered direct load (volatile: mutual order kept; result valid only after
// an explicit vmcnt drain that follows within the same batch)
#define LDX4(dst, ptr) \
  asm volatile("global_load_dwordx4 %0, %1, off" : "=&v"(dst) : "v"(ptr))

// ---------------- prep kernels ----------------
__global__ void f2b(const float* __restrict__ in, bf16_t* __restrict__ outp, int n){
  int i = (blockIdx.x*256 + threadIdx.x)*4;
  if (i >= n) return;
  float4 v = *(const float4*)(in + i);
  bf16x4 o; o[0]=(bf16_t)v.x; o[1]=(bf16_t)v.y; o[2]=(bf16_t)v.z; o[3]=(bf16_t)v.w;
  *(bf16x4*)(outp + i) = o;
}

__global__ void f2b_pair(const float* __restrict__ in, bf16_t* __restrict__ oh,
                         bf16_t* __restrict__ ol, int n){
  int i = (blockIdx.x*256 + threadIdx.x)*4;
  if (i >= n) return;
  float4 v = *(const float4*)(in + i);
  float vv[4] = {v.x, v.y, v.z, v.w};
  bf16x4 h, l;
  #pragma unroll
  for (int j=0;j<4;j++){ h[j]=(bf16_t)vv[j]; l[j]=(bf16_t)(vv[j]-(float)h[j]); }
  *(bf16x4*)(oh + i) = h;
  *(bf16x4*)(ol + i) = l;
}

__global__ void bias_combine(const float* __restrict__ a, const float* __restrict__ b,
                             float* __restrict__ o, int n){
  int i = blockIdx.x*256 + threadIdx.x;
  if (i < n) o[i] = a[i] + b[i];
}

__global__ void embed_gather(const int* __restrict__ tokp, const float* __restrict__ embW,
                             bf16_t* __restrict__ xe){
  int m = blockIdx.x;
  int tokv = tokp[m];
  const float* src = embW + (size_t)tokv*1024 + threadIdx.x*4;
  float4 v = *(const float4*)src;
  bf16x4 o; o[0]=(bf16_t)v.x; o[1]=(bf16_t)v.y; o[2]=(bf16_t)v.z; o[3]=(bf16_t)v.w;
  *(bf16x4*)(xe + (size_t)m*1024 + threadIdx.x*4) = o;
}

// winT[e,d] = split(Win[d,e])
__global__ void transWin(const float* __restrict__ in, bf16_t* __restrict__ oh,
                         bf16_t* __restrict__ ol){
  __shared__ float t[32][33];
  int bi = blockIdx.x & 31, bj = blockIdx.x >> 5;
  int tx = threadIdx.x & 31, ty = threadIdx.x >> 5;  // 32 x 8
  #pragma unroll
  for (int i=0;i<4;i++){
    int d = bi*32 + ty + i*8, e = bj*32 + tx;
    t[ty+i*8][tx] = in[(size_t)d*1024 + e];
  }
  __syncthreads();
  #pragma unroll
  for (int i=0;i<4;i++){
    int e = bj*32 + ty + i*8, d = bi*32 + tx;
    float v = t[tx][ty+i*8];
    bf16_t h = (bf16_t)v;
    oh[(size_t)e*1024 + d] = h;
    ol[(size_t)e*1024 + d] = (bf16_t)(v - (float)h);
  }
}

// -------- x0g GEMM: x0gT[t][bg][g][col][16 rows] = xemb@wih0^T + bias0 --------
__global__ __launch_bounds__(256) void gemm_bt(
    const bf16_t* __restrict__ A, const bf16_t* __restrict__ Bm,
    const float* __restrict__ bias, bf16_t* __restrict__ Cout,
    int M, int N, int K, int nTN)
{
  __shared__ bf16_t sA[128*64];
  __shared__ bf16_t sB[128*64];
  int tid = threadIdx.x, lane = tid & 63, w = tid >> 6;
  int tm = blockIdx.x / nTN, tn = blockIdx.x % nTN;
  int row0 = tm*128, col0 = tn*128;
  int wr = w >> 1, wcc = w & 1;
  f32x4 acc[4][4] = {};
  for (int kt = 0; kt < K; kt += 64) {
    __syncthreads();
    #pragma unroll
    for (int i=0;i<4;i++){
      int c = i*256 + tid;
      int r = c >> 3, kk = (c & 7) << 3;
      gll16(A  + (size_t)(row0+r)*K + kt + kk, sA + (size_t)(i*256 + w*64)*8);
      gll16(Bm + (size_t)(col0+r)*K + kt + kk, sB + (size_t)(i*256 + w*64)*8);
    }
    __syncthreads();
    #pragma unroll
    for (int kk=0;kk<64;kk+=32){
      bf16x8 av[4], bv[4];
      #pragma unroll
      for (int m=0;m<4;m++) av[m] = *(const bf16x8*)(sA + (wr*64 + m*16 + (lane&15))*64 + kk + ((lane>>4)<<3));
      #pragma unroll
      for (int n=0;n<4;n++) bv[n] = *(const bf16x8*)(sB + (wcc*64 + n*16 + (lane&15))*64 + kk + ((lane>>4)<<3));
      #pragma unroll
      for (int m=0;m<4;m++)
        #pragma unroll
        for (int n=0;n<4;n++)
          acc[m][n] = __builtin_amdgcn_mfma_f32_16x16x32_bf16(av[m], bv[n], acc[m][n], 0,0,0);
    }
  }
  #pragma unroll
  for (int n=0;n<4;n++){
    int cn = col0 + wcc*64 + n*16 + (lane & 15);
    float bvv = bias[cn];
    int g = cn >> 10, col = cn & 1023;
    #pragma unroll
    for (int m=0;m<4;m++){
      int rm = row0 + wr*64 + m*16 + ((lane>>4)<<2);
      int p = rm >> 7, bgi = (rm >> 4) & 7, rr = rm & 15;
      bf16x4 o;
      #pragma unroll
      for (int r=0;r<4;r++) o[r] = (bf16_t)(acc[m][n][r] + bvv);
      *(bf16x4*)(Cout + ((((size_t)p*8+bgi)*4+g)*1024 + col)*16 + rr) = o;
    }
  }
}

// ---------------- split GEMM: hi/lo A (two K-parts) x hi/lo B, 3 combos ----------------
template<int ACT_TANH, int OUT_PAIR>
__global__ __launch_bounds__(256) void gemm_split(
    const bf16_t* __restrict__ Ah1, const bf16_t* __restrict__ Al1,
    const bf16_t* __restrict__ Ah2, const bf16_t* __restrict__ Al2, int K1,
    const bf16_t* __restrict__ Bh, const bf16_t* __restrict__ Bl,
    float* __restrict__ Cf, bf16_t* __restrict__ Ch, bf16_t* __restrict__ Cl,
    int M, int N, int K, int nTN)
{
  __shared__ bf16_t sAh[128*64], sAl[128*64], sBh[128*64], sBl[128*64];
  int tid = threadIdx.x, lane = tid & 63, w = tid >> 6;
  int tm = blockIdx.x / nTN, tn = blockIdx.x % nTN;
  int row0 = tm*128, col0 = tn*128;
  int wr = w >> 1, wcc = w & 1;
  f32x4 acc[4][4] = {};
  for (int kt = 0; kt < K; kt += 64) {
    const bf16_t *Ah, *Al; int kl;
    if (kt < K1){ Ah=Ah1; Al=Al1; kl=kt; } else { Ah=Ah2; Al=Al2; kl=kt-K1; }
    __syncthreads();
    #pragma unroll
    for (int i=0;i<4;i++){
      int c = i*256 + tid;
      int r = c >> 3, kk = (c & 7) << 3;
      gll16(Ah + (size_t)(row0+r)*K1 + kl + kk, sAh + (size_t)(i*256 + w*64)*8);
      gll16(Al + (size_t)(row0+r)*K1 + kl + kk, sAl + (size_t)(i*256 + w*64)*8);
      gll16(Bh + (size_t)(col0+r)*K + kt + kk, sBh + (size_t)(i*256 + w*64)*8);
      gll16(Bl + (size_t)(col0+r)*K + kt + kk, sBl + (size_t)(i*256 + w*64)*8);
    }
    __syncthreads();
    #pragma unroll
    for (int kk=0;kk<64;kk+=32){
      bf16x8 avh[4], avl[4], bvh[4], bvl[4];
      #pragma unroll
      for (int m=0;m<4;m++){
        int off = (wr*64 + m*16 + (lane&15))*64 + kk + ((lane>>4)<<3);
        avh[m] = *(const bf16x8*)(sAh + off);
        avl[m] = *(const bf16x8*)(sAl + off);
      }
      #pragma unroll
      for (int n=0;n<4;n++){
        int off = (wcc*64 + n*16 + (lane&15))*64 + kk + ((lane>>4)<<3);
        bvh[n] = *(const bf16x8*)(sBh + off);
        bvl[n] = *(const bf16x8*)(sBl + off);
      }
      #pragma unroll
      for (int m=0;m<4;m++)
        #pragma unroll
        for (int n=0;n<4;n++){
          acc[m][n] = __builtin_amdgcn_mfma_f32_16x16x32_bf16(avh[m], bvh[n], acc[m][n], 0,0,0);
          acc[m][n] = __builtin_amdgcn_mfma_f32_16x16x32_bf16(avl[m], bvh[n], acc[m][n], 0,0,0);
          acc[m][n] = __builtin_amdgcn_mfma_f32_16x16x32_bf16(avh[m], bvl[n], acc[m][n], 0,0,0);
        }
    }
  }
  #pragma unroll
  for (int n=0;n<4;n++){
    int cn = col0 + wcc*64 + n*16 + (lane & 15);
    #pragma unroll
    for (int m=0;m<4;m++){
      int rm = row0 + wr*64 + m*16 + ((lane>>4)<<2);
      #pragma unroll
      for (int r=0;r<4;r++){
        float v = acc[m][n][r];
        if (ACT_TANH) v = tanhf(v);
        if (OUT_PAIR){
          bf16_t h = (bf16_t)v;
          Ch[(size_t)(rm+r)*N + cn] = h;
          Cl[(size_t)(rm+r)*N + cn] = (bf16_t)(v - (float)h);
        } else {
          Cf[(size_t)(rm+r)*N + cn] = v;
        }
      }
    }
  }
}

// ---------------- persistent LSTM loop: weights in LDS, h direct to VGPR ----------------
// 256 blocks x 1024 thr (16 waves = 8 row-groups rg x 2 K-halves kh).
// Block owns 4 hidden cols. Weights [48][1032] in LDS. h loaded in batches of
// 8 volatile-asm dwordx4 (2 chunks x 4 arrays), drained in-batch, MFMA'd.
#define NBLK 256
#define WST  1032
#define SGOFF 99072                    // 48*1032*2 bytes of weights
#define LDS_BYTES (99072 + 4*2176*4)   // 133888: + sG 4 regions [128][17] f32

__global__ __launch_bounds__(1024, 4) void lstm_loop(
    const bf16_t* __restrict__ whh0, const bf16_t* __restrict__ wih1,
    const bf16_t* __restrict__ whh1, const bf16_t* __restrict__ x0gT,
    const float* __restrict__ bias1, const float* __restrict__ c0in,
    bf16_t* __restrict__ h0h, bf16_t* __restrict__ h0l,     // hist [65][128][1024]
    bf16_t* __restrict__ h1h, bf16_t* __restrict__ h1l,     // hist [65][128][1024]
    float* __restrict__ outH, float* __restrict__ outC, int* bar)
{
  extern __shared__ char smem[];
  bf16_t* wlds = (bf16_t*)smem;
  float*  sG   = (float*)(smem + SGOFF);

  // one-time acquire: invalidate stale L1/L2 lines (poison / prior replay)
  __threadfence();

  const int tid = threadIdx.x, lane = tid & 63, wv = tid >> 6;
  const int l15 = lane & 15, hi4 = lane >> 4;
  const int hc0 = blockIdx.x * 4;
  const int rg = wv & 7, kh = wv >> 3;

  // ---- stage weights into LDS once (padded rows -> bank spread) ----
  for (int e = tid; e < 6144; e += 1024){
    int m = e >> 11, r = e & 2047, n = r >> 7, kc = r & 127;
    const bf16_t* Wm = (m == 0) ? whh0 : ((m == 1) ? wih1 : whh1);
    int row = ((n >> 2) << 10) + hc0 + (n & 3);
    bf16x8 v = *(const bf16x8*)(Wm + (size_t)row*1024 + kc*8);
    *(bf16x8*)(wlds + (size_t)(m*16 + n)*WST + kc*8) = v;
  }
  __syncthreads();

  // cell mapping: threads 0..511 own 1 cell per layer
  const bool cell = (tid < 512);
  const int crow = tid >> 2, q = tid & 3;
  const size_t cellix = (size_t)crow*1024 + hc0 + q;
  float c0reg = 0.f, c1reg = 0.f, bs[4] = {};
  if (cell){
    c0reg = c0in[cellix];
    c1reg = c0in[131072 + cellix];
    #pragma unroll
    for (int g=0; g<4; ++g) bs[g] = bias1[(g<<10) + hc0 + q];
  }

  // per-lane h element offset: row rg*16 + l15, k base kh*512 + hi4*8
  const size_t aoff = (size_t)(rg*16 + l15)*1024 + (size_t)(kh*512 + hi4*8);
  // weight read row bases (padded)
  const int wbA = (0*16 + l15)*WST;
  const int wbB = (1*16 + l15)*WST;
  const int wbC = (2*16 + l15)*WST;

  for (int p = 0; p <= 64; ++p){
    const bf16_t* h0h_ = h0h + (size_t)p*131072 + aoff;
    const bf16_t* h0l_ = h0l + (size_t)p*131072 + aoff;
    const bf16_t* h1ph = h1h + (size_t)(p >= 1 ? p-1 : 0)*131072 + aoff;
    const bf16_t* h1pl = h1l + (size_t)(p >= 1 ? p-1 : 0)*131072 + aoff;

    // x0g loads (dense transposed layout); compiler-managed waitcnt
    float xg[4] = {0,0,0,0};
    if (cell && p < 64){
      int bg = crow >> 4, rr = crow & 15;
      #pragma unroll
      for (int g=0; g<4; ++g)
        xg[g] = (float)x0gT[((((size_t)p*8 + bg)*4 + g)*1024 + hc0 + q)*16 + rr];
    }

    // ---- K-loop: 8 batches x (2 chunks x 4 arrays direct loads + 12 MFMA) ----
    f32x4 accA = {}, accB = {};
    #pragma unroll
    for (int cc = 0; cc < 8; ++cc){
      const int c0 = cc*2, c1 = cc*2 + 1;
      f32x4 t0,t1,t2,t3,t4,t5,t6,t7;
      LDX4(t0, h0h_ + c0*32); LDX4(t1, h0l_ + c0*32);
      LDX4(t2, h1ph + c0*32); LDX4(t3, h1pl + c0*32);
      LDX4(t4, h0h_ + c1*32); LDX4(t5, h0l_ + c1*32);
      LDX4(t6, h1ph + c1*32); LDX4(t7, h1pl + c1*32);
      asm volatile("s_waitcnt vmcnt(0)" ::: "memory");
      __builtin_amdgcn_sched_barrier(0);
      bf16x8 a0h = __builtin_bit_cast(bf16x8, t0);
      bf16x8 a0l = __builtin_bit_cast(bf16x8, t1);
      bf16x8 b0h = __builtin_bit_cast(bf16x8, t2);
      bf16x8 b0l = __builtin_bit_cast(bf16x8, t3);
      bf16x8 a1h = __builtin_bit_cast(bf16x8, t4);
      bf16x8 a1l = __builtin_bit_cast(bf16x8, t5);
      bf16x8 b1h = __builtin_bit_cast(bf16x8, t6);
      bf16x8 b1l = __builtin_bit_cast(bf16x8, t7);
      const int ge0 = (kh*64 + c0*4 + hi4)*8;
      const int ge1 = (kh*64 + c1*4 + hi4)*8;
      bf16x8 w00 = *(const bf16x8*)(wlds + wbA + ge0);
      bf16x8 w01 = *(const bf16x8*)(wlds + wbB + ge0);
      bf16x8 w02 = *(const bf16x8*)(wlds + wbC + ge0);
      bf16x8 w10 = *(const bf16x8*)(wlds + wbA + ge1);
      bf16x8 w11 = *(const bf16x8*)(wlds + wbB + ge1);
      bf16x8 w12 = *(const bf16x8*)(wlds + wbC + ge1);
      MFMA16(accA, a0h, w00); MFMA16(accA, a0l, w00);
      MFMA16(accB, a0h, w01); MFMA16(accB, a0l, w01);
      MFMA16(accB, b0h, w02); MFMA16(accB, b0l, w02);
      MFMA16(accA, a1h, w10); MFMA16(accA, a1l, w10);
      MFMA16(accB, a1h, w11); MFMA16(accB, a1l, w11);
      MFMA16(accB, b1h, w12); MFMA16(accB, b1l, w12);
    }

    // ---- gate exchange via sG ----
    __syncthreads();
    {
      const int rowb = rg*16 + hi4*4;
      #pragma unroll
      for (int r=0;r<4;r++){
        sG[(0*2 + kh)*2176 + (rowb + r)*17 + l15] = accA[r];
        sG[(2 + kh)*2176 + (rowb + r)*17 + l15]   = accB[r];
      }
    }
    __syncthreads();

    // ---- cells ----
    if (cell){
      if (p < 64){
        float gv[4];
        #pragma unroll
        for (int g=0; g<4; ++g)
          gv[g] = sG[0*2176 + crow*17 + g*4 + q] + sG[1*2176 + crow*17 + g*4 + q] + xg[g];
        float cv = sigm(gv[1])*c0reg + sigm(gv[0])*tanhf(gv[2]);
        float hv = sigm(gv[3])*tanhf(cv);
        c0reg = cv;
        bf16_t hh = (bf16_t)hv;
        stg_sc(h0h + (size_t)(p+1)*131072 + cellix, hh);
        stg_sc(h0l + (size_t)(p+1)*131072 + cellix, (bf16_t)(hv - (float)hh));
        if (p == 63){ outH[cellix] = hv; outC[cellix] = cv; }
      }
      if (p >= 1){
        float gv[4];
        #pragma unroll
        for (int g=0; g<4; ++g)
          gv[g] = sG[2*2176 + crow*17 + g*4 + q] + sG[3*2176 + crow*17 + g*4 + q] + bs[g];
        float cv = sigm(gv[1])*c1reg + sigm(gv[0])*tanhf(gv[2]);
        float hv = sigm(gv[3])*tanhf(cv);
        c1reg = cv;
        bf16_t hh = (bf16_t)hv;
        stg_sc(h1h + (size_t)p*131072 + cellix, hh);
        stg_sc(h1l + (size_t)p*131072 + cellix, (bf16_t)(hv - (float)hh));
        if (p == 64){ outH[131072 + cellix] = hv; outC[131072 + cellix] = cv; }
      }
    }

    // ---- grid barrier (fence-free; 16 spread sub-counters) ----
    if (p < 64){
      __syncthreads();   // drains each wave's vmem (incl. sc stores)
      if (tid == 0){
        __hip_atomic_fetch_add(bar + (blockIdx.x & 15)*64, 1, __ATOMIC_RELAXED, __HIP_MEMORY_SCOPE_AGENT);
        const int tgt = NBLK*(p+1);
        for(;;){
          int s = 0;
          #pragma unroll
          for (int i=0;i<16;i++)
            s += __hip_atomic_load(bar + i*64, __ATOMIC_RELAXED, __HIP_MEMORY_SCOPE_AGENT);
          if (s >= tgt) break;
          __builtin_amdgcn_s_sleep(2);
        }
      }
      __syncthreads();
      asm volatile("" ::: "memory");
      __builtin_amdgcn_sched_barrier(0);
    }
  }
}

// ---------------- scores + softmax (per batch row b), post-loop ----------------
__global__ __launch_bounds__(256) void attn_sm(
    const bf16_t* __restrict__ h1h, const bf16_t* __restrict__ h1l,
    const bf16_t* __restrict__ cwh, const bf16_t* __restrict__ cwl,
    float* __restrict__ a_all, float* __restrict__ outA)
{
  __shared__ bf16_t sAh[64*64], sAl[64*64];
  __shared__ bf16_t sBh[128*64], sBl[128*64];
  __shared__ float sS[64*128];
  int b = blockIdx.x;
  int tid = threadIdx.x, lane = tid&63, w = tid>>6;
  int wr = w>>1, wcc = w&1;
  f32x4 acc[2][4] = {};
  for (int kt=0; kt<1024; kt+=64){
    __syncthreads();
    #pragma unroll
    for (int i=0;i<2;i++){
      int c = i*256+tid; int r = c>>3, kk=(c&7)<<3;
      size_t src = (size_t)(r+1)*131072 + (size_t)b*1024 + kt+kk;
      gll16(h1h + src, sAh + (size_t)(i*256 + w*64)*8);
      gll16(h1l + src, sAl + (size_t)(i*256 + w*64)*8);
    }
    #pragma unroll
    for (int i=0;i<4;i++){
      int c = i*256+tid; int br=c>>3, kk=(c&7)<<3;
      size_t src = ((size_t)b*128 + br)*1024 + kt+kk;
      gll16(cwh + src, sBh + (size_t)(i*256+w*64)*8);
      gll16(cwl + src, sBl + (size_t)(i*256+w*64)*8);
    }
    __syncthreads();
    #pragma unroll
    for (int kk=0;kk<64;kk+=32){
      bf16x8 avh[2], avl[2], bvh[4], bvl[4];
      #pragma unroll
      for (int m=0;m<2;m++){
        int off = (wr*32 + m*16 + (lane&15))*64 + kk + ((lane>>4)<<3);
        avh[m] = *(const bf16x8*)(sAh + off);
        avl[m] = *(const bf16x8*)(sAl + off);
      }
      #pragma unroll
      for (int n=0;n<4;n++){
        int off = (wcc*64 + n*16 + (lane&15))*64 + kk + ((lane>>4)<<3);
        bvh[n] = *(const bf16x8*)(sBh + off);
        bvl[n] = *(const bf16x8*)(sBl + off);
      }
      #pragma unroll
      for (int m=0;m<2;m++)
        #pragma unroll
        for (int n=0;n<4;n++){
          acc[m][n] = __builtin_amdgcn_mfma_f32_16x16x32_bf16(avh[m], bvh[n], acc[m][n], 0,0,0);
          acc[m][n] = __builtin_amdgcn_mfma_f32_16x16x32_bf16(avl[m], bvh[n], acc[m][n], 0,0,0);
          acc[m][n] = __builtin_amdgcn_mfma_f32_16x16x32_bf16(avh[m], bvl[n], acc[m][n], 0,0,0);
        }
    }
  }
  #pragma unroll
  for (int m=0;m<2;m++)
    #pragma unroll
    for (int n=0;n<4;n++)
      #pragma unroll
      for (int r=0;r<4;r++){
        int trow = wr*32 + m*16 + ((lane>>4)<<2) + r;
        int tc   = wcc*64 + n*16 + (lane&15);
        sS[trow*128+tc] = acc[m][n][r];
      }
  __syncthreads();
  for (int i=0;i<16;i++){
    int r = w*16 + i;
    float v0 = sS[r*128 + lane], v1 = sS[r*128 + 64 + lane];
    float mx = fmaxf(v0, v1);
    #pragma unroll
    for (int off=32; off; off>>=1) mx = fmaxf(mx, __shfl_xor(mx, off));
    float e0 = expf(v0-mx), e1 = expf(v1-mx);
    float sm = e0+e1;
    #pragma unroll
    for (int off=32; off; off>>=1) sm += __shfl_xor(sm, off);
    float inv = 1.f/sm;
    size_t base = ((size_t)r*128 + b)*128;
    a_all[base + lane]      = e0*inv;
    a_all[base + 64 + lane] = e1*inv;
    if (r == 63){
      outA[(size_t)b*128 + lane]      = e0*inv;
      outA[(size_t)b*128 + 64 + lane] = e1*inv;
    }
  }
}

// ---------------- wc (fp32 VALU): wc[t,b,:] = sum_s a[t,b,s]*ctx[b,s,:] ----
__global__ __launch_bounds__(256) void wc_all(
    const float* __restrict__ a_all, const float* __restrict__ ctx,
    bf16_t* __restrict__ wch, bf16_t* __restrict__ wcl)
{
  int bid = blockIdx.x;
  int b = bid & 127, tg = bid >> 7;  // tg 0..3, 16 t each
  int tid = threadIdx.x;
  __shared__ float sa[16][128];
  int t0 = tg*16;
  #pragma unroll
  for (int i=0;i<8;i++){
    int q = i*256 + tid;
    int ti = q >> 7, s = q & 127;
    sa[ti][s] = a_all[((size_t)(t0+ti)*128 + b)*128 + s];
  }
  __syncthreads();
  f32x4 acc[16];
  #pragma unroll
  for (int i=0;i<16;i++) acc[i] = f32x4{0,0,0,0};
  const float* cb = ctx + (size_t)b*128*1024 + tid*4;
  for (int s=0;s<128;s++){
    f32x4 c = *(const f32x4*)(cb + (size_t)s*1024);
    #pragma unroll
    for (int ti=0;ti<16;ti++){
      float av = sa[ti][s];
      acc[ti] += av * c;
    }
  }
  #pragma unroll
  for (int ti=0;ti<16;ti++){
    size_t m = (size_t)(t0+ti)*128 + b;
    bf16x4 h, l;
    #pragma unroll
    for (int j=0;j<4;j++){
      float v = acc[ti][j];
      h[j] = (bf16_t)v; l[j] = (bf16_t)(v - (float)h[j]);
    }
    *(bf16x4*)(wch + m*1024 + tid*4) = h;
    *(bf16x4*)(wcl + m*1024 + tid*4) = l;
  }
}

// ---------------- host ----------------
extern "C" void kernel_launch(void* const* d_in, const int* in_sizes, int n_in,
                              void* d_out, int out_size, void* d_ws, size_t ws_size,
                              hipStream_t stream)
{
  (void)in_sizes; (void)n_in; (void)out_size; (void)ws_size;
  const int TT=64, BB=128, H=1024, G=4096, BH=128*1024;

  const int*   tok  = (const int*)d_in[0];
  const float* h0   = (const float*)d_in[1];
  const float* c0   = (const float*)d_in[2];
  const float* ctx  = (const float*)d_in[3];
  const float* embW = (const float*)d_in[5];
  const float* wih  = (const float*)d_in[6];
  const float* whh  = (const float*)d_in[7];
  const float* bih  = (const float*)d_in[8];
  const float* bhh  = (const float*)d_in[9];
  const float* Win  = (const float*)d_in[10];
  const float* Wout = (const float*)d_in[11];

  float* outY = (float*)d_out;                      // [T,B,H]
  float* outH = outY + (size_t)TT*BB*H;             // [2,B,H]
  float* outC = outH + (size_t)2*BH;                // [2,B,H]
  float* outA = outC + (size_t)2*BH;                // [B,S]

  char* ws = (char*)d_ws;
  size_t o = 0;
  auto carve = [&](size_t bytes)->char* {
    char* p = ws + o; o += (bytes + 255) & ~(size_t)255; return p;
  };
  bf16_t* wihB  = (bf16_t*)carve((size_t)2*G*H*2);       // 16MB
  bf16_t* whhB  = (bf16_t*)carve((size_t)2*G*H*2);       // 16MB
  bf16_t* woutH = (bf16_t*)carve((size_t)H*2*H*2);       // 4MB
  bf16_t* woutL = (bf16_t*)carve((size_t)H*2*H*2);       // 4MB
  bf16_t* winTh = (bf16_t*)carve((size_t)H*H*2);         // 2MB
  bf16_t* winTl = (bf16_t*)carve((size_t)H*H*2);         // 2MB
  bf16_t* ctxh  = (bf16_t*)carve((size_t)BB*128*H*2);    // 32MB; loop: h0 hist hi; post: wch
  bf16_t* ctxl  = (bf16_t*)carve((size_t)BB*128*H*2);    // 32MB; loop: h0 hist lo; post: wcl
  bf16_t* cwh   = (bf16_t*)carve((size_t)BB*128*H*2);    // 32MB (pre: xemb overlays)
  bf16_t* cwl   = (bf16_t*)carve((size_t)BB*128*H*2);    // 32MB
  bf16_t* x0gT  = (bf16_t*)carve((size_t)TT*BB*G*2);     // 64MB
  bf16_t* h1h   = (bf16_t*)carve((size_t)(TT+1)*BH*2);   // 17MB history
  bf16_t* h1l   = (bf16_t*)carve((size_t)(TT+1)*BH*2);   // 17MB
  float*  a_all = (float*)carve((size_t)TT*BB*128*4);    // 4MB
  float*  biasF = (float*)carve((size_t)2*G*4);
  int*    bar   = (int*)carve(16*64*4);

  bf16_t* xemb   = cwh;          // overlays ctxW-hi (dead until ctxW GEMM)
  bf16_t* h0hist = ctxh;         // h0 history [65][128][1024] (ctx dead after ctxW GEMM)
  bf16_t* h0histl= ctxl;
  bf16_t* wch    = ctxh;         // post-loop overlay (h0 hist dead then)
  bf16_t* wcl    = ctxl;

  // ---- prep ----
  hipMemsetAsync(bar, 0, 16*64*4, stream);
  f2b<<<(2*G*H)/1024, 256, 0, stream>>>(wih, wihB, 2*G*H);
  f2b<<<(2*G*H)/1024, 256, 0, stream>>>(whh, whhB, 2*G*H);
  f2b_pair<<<(H*2*H)/1024, 256, 0, stream>>>(Wout, woutH, woutL, H*2*H);
  f2b_pair<<<(BB*128*H)/1024, 256, 0, stream>>>(ctx, ctxh, ctxl, BB*128*H);
  f2b_pair<<<BH/1024, 256, 0, stream>>>(h0 + BH, h1h, h1l, BH);
  transWin<<<1024, 256, 0, stream>>>(Win, winTh, winTl);
  bias_combine<<<(2*G)/256, 256, 0, stream>>>(bih, bhh, biasF, 2*G);
  embed_gather<<<TT*BB, 256, 0, stream>>>(tok, embW, xemb);

  // ---- one-time GEMMs ----
  gemm_bt<<<(TT*BB/128)*(G/128), 256, 0, stream>>>(xemb, wihB, biasF, x0gT, TT*BB, G, H, G/128);
  gemm_split<0,1><<<(BB*128/128)*(H/128), 256, 0, stream>>>(
      ctxh, ctxl, ctxh, ctxl, H, winTh, winTl,
      nullptr, cwh, cwl, BB*128, H, H, H/128);

  // h0 layer-0 initial state -> h0 history slot 0 (ctx region now dead)
  f2b_pair<<<BH/1024, 256, 0, stream>>>(h0, h0hist, h0histl, BH);

  // ---- persistent recurrence ----
  hipFuncSetAttribute((const void*)lstm_loop,
                      hipFuncAttributeMaxDynamicSharedMemorySize, LDS_BYTES);
  lstm_loop<<<NBLK, 1024, LDS_BYTES, stream>>>(
      whhB, wihB + (size_t)G*H, whhB + (size_t)G*H, x0gT, biasF + G, c0,
      h0hist, h0histl, h1h, h1l, outH, outC, bar);

  // ---- post-loop attention ----
  attn_sm<<<BB, 256, 0, stream>>>(h1h, h1l, cwh, cwl, a_all, outA);
  wc_all<<<BB*4, 256, 0, stream>>>(a_all, ctx, wch, wcl);

  gemm_split<1,0><<<(TT*BB/128)*(H/128), 256, 0, stream>>>(
      wch, wcl, h1h + BH, h1l + BH, H, woutH, woutL,
      outY, nullptr, nullptr, TT*BB, H, 2*H, H/128);
}

// Round 17
// 2260.689 us; speedup vs baseline: 1.2580x; 1.2580x over previous
//
#include <hip/hip_runtime.h>
#include <hip/hip_bf16.h>
#include <stdint.h>

// Decoder: 2-layer LSTM + Luong attention. input_feed=0 => attention deferred
// post-loop. R17 = R14 (weights in LDS, 16 waves, async gll16 h staging,
// fence-free barrier) with h-state stores converted from sc0sc1 write-through
// (which pushes to HBM without L3 allocation -> every phase re-reads h from
// HBM) to non-returning global_atomic_swap_x2: atomics execute AND ALLOCATE
// at L3 (coherence point), so next-phase reads hit L3, not HBM.

typedef __bf16 bf16_t;
typedef __bf16 bf16x8 __attribute__((ext_vector_type(8)));
typedef __bf16 bf16x4 __attribute__((ext_vector_type(4)));
typedef float f32x4 __attribute__((ext_vector_type(4)));

#define AS1 __attribute__((address_space(1)))
#define AS3 __attribute__((address_space(3)))

__device__ __forceinline__ void gll16(const bf16_t* g, bf16_t* l) {
  __builtin_amdgcn_global_load_lds((const AS1 void*)g, (AS3 void*)l, 16, 0, 0);
}

__device__ __forceinline__ float sigm(float x){ return 1.f/(1.f+expf(-x)); }

#define MFMA16(acc, a, b) acc = __builtin_amdgcn_mfma_f32_16x16x32_bf16(a, b, acc, 0,0,0)

// h-state store: non-returning 64b atomic swap -> lands & stays in L3
// (coherence point; device-scope; visible to all XCDs; NOT pushed to HBM).
__device__ __forceinline__ void atom_sw64(bf16_t* p, uint64_t v){
  asm volatile("global_atomic_swap_x2 %0, %1, off" :: "v"(p), "v"(v) : "memory");
}

// ---------------- prep kernels ----------------
__global__ void f2b(const float* __restrict__ in, bf16_t* __restrict__ outp, int n){
  int i = (blockIdx.x*256 + threadIdx.x)*4;
  if (i >= n) return;
  float4 v = *(const float4*)(in + i);
  bf16x4 o; o[0]=(bf16_t)v.x; o[1]=(bf16_t)v.y; o[2]=(bf16_t)v.z; o[3]=(bf16_t)v.w;
  *(bf16x4*)(outp + i) = o;
}

__global__ void f2b_pair(const float* __restrict__ in, bf16_t* __restrict__ oh,
                         bf16_t* __restrict__ ol, int n){
  int i = (blockIdx.x*256 + threadIdx.x)*4;
  if (i >= n) return;
  float4 v = *(const float4*)(in + i);
  float vv[4] = {v.x, v.y, v.z, v.w};
  bf16x4 h, l;
  #pragma unroll
  for (int j=0;j<4;j++){ h[j]=(bf16_t)vv[j]; l[j]=(bf16_t)(vv[j]-(float)h[j]); }
  *(bf16x4*)(oh + i) = h;
  *(bf16x4*)(ol + i) = l;
}

__global__ void bias_combine(const float* __restrict__ a, const float* __restrict__ b,
                             float* __restrict__ o, int n){
  int i = blockIdx.x*256 + threadIdx.x;
  if (i < n) o[i] = a[i] + b[i];
}

__global__ void embed_gather(const int* __restrict__ tokp, const float* __restrict__ embW,
                             bf16_t* __restrict__ xe){
  int m = blockIdx.x;
  int tokv = tokp[m];
  const float* src = embW + (size_t)tokv*1024 + threadIdx.x*4;
  float4 v = *(const float4*)src;
  bf16x4 o; o[0]=(bf16_t)v.x; o[1]=(bf16_t)v.y; o[2]=(bf16_t)v.z; o[3]=(bf16_t)v.w;
  *(bf16x4*)(xe + (size_t)m*1024 + threadIdx.x*4) = o;
}

// winT[e,d] = split(Win[d,e])
__global__ void transWin(const float* __restrict__ in, bf16_t* __restrict__ oh,
                         bf16_t* __restrict__ ol){
  __shared__ float t[32][33];
  int bi = blockIdx.x & 31, bj = blockIdx.x >> 5;
  int tx = threadIdx.x & 31, ty = threadIdx.x >> 5;  // 32 x 8
  #pragma unroll
  for (int i=0;i<4;i++){
    int d = bi*32 + ty + i*8, e = bj*32 + tx;
    t[ty+i*8][tx] = in[(size_t)d*1024 + e];
  }
  __syncthreads();
  #pragma unroll
  for (int i=0;i<4;i++){
    int e = bj*32 + ty + i*8, d = bi*32 + tx;
    float v = t[tx][ty+i*8];
    bf16_t h = (bf16_t)v;
    oh[(size_t)e*1024 + d] = h;
    ol[(size_t)e*1024 + d] = (bf16_t)(v - (float)h);
  }
}

// -------- x0g GEMM: x0gT[t][bg][g][col][16 rows] = xemb@wih0^T + bias0 --------
__global__ __launch_bounds__(256) void gemm_bt(
    const bf16_t* __restrict__ A, const bf16_t* __restrict__ Bm,
    const float* __restrict__ bias, bf16_t* __restrict__ Cout,
    int M, int N, int K, int nTN)
{
  __shared__ bf16_t sA[128*64];
  __shared__ bf16_t sB[128*64];
  int tid = threadIdx.x, lane = tid & 63, w = tid >> 6;
  int tm = blockIdx.x / nTN, tn = blockIdx.x % nTN;
  int row0 = tm*128, col0 = tn*128;
  int wr = w >> 1, wcc = w & 1;
  f32x4 acc[4][4] = {};
  for (int kt = 0; kt < K; kt += 64) {
    __syncthreads();
    #pragma unroll
    for (int i=0;i<4;i++){
      int c = i*256 + tid;
      int r = c >> 3, kk = (c & 7) << 3;
      gll16(A  + (size_t)(row0+r)*K + kt + kk, sA + (size_t)(i*256 + w*64)*8);
      gll16(Bm + (size_t)(col0+r)*K + kt + kk, sB + (size_t)(i*256 + w*64)*8);
    }
    __syncthreads();
    #pragma unroll
    for (int kk=0;kk<64;kk+=32){
      bf16x8 av[4], bv[4];
      #pragma unroll
      for (int m=0;m<4;m++) av[m] = *(const bf16x8*)(sA + (wr*64 + m*16 + (lane&15))*64 + kk + ((lane>>4)<<3));
      #pragma unroll
      for (int n=0;n<4;n++) bv[n] = *(const bf16x8*)(sB + (wcc*64 + n*16 + (lane&15))*64 + kk + ((lane>>4)<<3));
      #pragma unroll
      for (int m=0;m<4;m++)
        #pragma unroll
        for (int n=0;n<4;n++)
          acc[m][n] = __builtin_amdgcn_mfma_f32_16x16x32_bf16(av[m], bv[n], acc[m][n], 0,0,0);
    }
  }
  #pragma unroll
  for (int n=0;n<4;n++){
    int cn = col0 + wcc*64 + n*16 + (lane & 15);
    float bvv = bias[cn];
    int g = cn >> 10, col = cn & 1023;
    #pragma unroll
    for (int m=0;m<4;m++){
      int rm = row0 + wr*64 + m*16 + ((lane>>4)<<2);
      int p = rm >> 7, bgi = (rm >> 4) & 7, rr = rm & 15;
      bf16x4 o;
      #pragma unroll
      for (int r=0;r<4;r++) o[r] = (bf16_t)(acc[m][n][r] + bvv);
      *(bf16x4*)(Cout + ((((size_t)p*8+bgi)*4+g)*1024 + col)*16 + rr) = o;
    }
  }
}

// ---------------- split GEMM: hi/lo A (two K-parts) x hi/lo B, 3 combos ----------------
template<int ACT_TANH, int OUT_PAIR>
__global__ __launch_bounds__(256) void gemm_split(
    const bf16_t* __restrict__ Ah1, const bf16_t* __restrict__ Al1,
    const bf16_t* __restrict__ Ah2, const bf16_t* __restrict__ Al2, int K1,
    const bf16_t* __restrict__ Bh, const bf16_t* __restrict__ Bl,
    float* __restrict__ Cf, bf16_t* __restrict__ Ch, bf16_t* __restrict__ Cl,
    int M, int N, int K, int nTN)
{
  __shared__ bf16_t sAh[128*64], sAl[128*64], sBh[128*64], sBl[128*64];
  int tid = threadIdx.x, lane = tid & 63, w = tid >> 6;
  int tm = blockIdx.x / nTN, tn = blockIdx.x % nTN;
  int row0 = tm*128, col0 = tn*128;
  int wr = w >> 1, wcc = w & 1;
  f32x4 acc[4][4] = {};
  for (int kt = 0; kt < K; kt += 64) {
    const bf16_t *Ah, *Al; int kl;
    if (kt < K1){ Ah=Ah1; Al=Al1; kl=kt; } else { Ah=Ah2; Al=Al2; kl=kt-K1; }
    __syncthreads();
    #pragma unroll
    for (int i=0;i<4;i++){
      int c = i*256 + tid;
      int r = c >> 3, kk = (c & 7) << 3;
      gll16(Ah + (size_t)(row0+r)*K1 + kl + kk, sAh + (size_t)(i*256 + w*64)*8);
      gll16(Al + (size_t)(row0+r)*K1 + kl + kk, sAl + (size_t)(i*256 + w*64)*8);
      gll16(Bh + (size_t)(col0+r)*K + kt + kk, sBh + (size_t)(i*256 + w*64)*8);
      gll16(Bl + (size_t)(col0+r)*K + kt + kk, sBl + (size_t)(i*256 + w*64)*8);
    }
    __syncthreads();
    #pragma unroll
    for (int kk=0;kk<64;kk+=32){
      bf16x8 avh[4], avl[4], bvh[4], bvl[4];
      #pragma unroll
      for (int m=0;m<4;m++){
        int off = (wr*64 + m*16 + (lane&15))*64 + kk + ((lane>>4)<<3);
        avh[m] = *(const bf16x8*)(sAh + off);
        avl[m] = *(const bf16x8*)(sAl + off);
      }
      #pragma unroll
      for (int n=0;n<4;n++){
        int off = (wcc*64 + n*16 + (lane&15))*64 + kk + ((lane>>4)<<3);
        bvh[n] = *(const bf16x8*)(sBh + off);
        bvl[n] = *(const bf16x8*)(sBl + off);
      }
      #pragma unroll
      for (int m=0;m<4;m++)
        #pragma unroll
        for (int n=0;n<4;n++){
          acc[m][n] = __builtin_amdgcn_mfma_f32_16x16x32_bf16(avh[m], bvh[n], acc[m][n], 0,0,0);
          acc[m][n] = __builtin_amdgcn_mfma_f32_16x16x32_bf16(avl[m], bvh[n], acc[m][n], 0,0,0);
          acc[m][n] = __builtin_amdgcn_mfma_f32_16x16x32_bf16(avh[m], bvl[n], acc[m][n], 0,0,0);
        }
    }
  }
  #pragma unroll
  for (int n=0;n<4;n++){
    int cn = col0 + wcc*64 + n*16 + (lane & 15);
    #pragma unroll
    for (int m=0;m<4;m++){
      int rm = row0 + wr*64 + m*16 + ((lane>>4)<<2);
      #pragma unroll
      for (int r=0;r<4;r++){
        float v = acc[m][n][r];
        if (ACT_TANH) v = tanhf(v);
        if (OUT_PAIR){
          bf16_t h = (bf16_t)v;
          Ch[(size_t)(rm+r)*N + cn] = h;
          Cl[(size_t)(rm+r)*N + cn] = (bf16_t)(v - (float)h);
        } else {
          Cf[(size_t)(rm+r)*N + cn] = v;
        }
      }
    }
  }
}

// ---------------- persistent LSTM loop: weights in LDS, async h staging ----------------
// 256 blocks x 1024 thr (16 waves = 8 row-groups rg x 2 K-halves kh).
// Block owns 4 hidden cols. Weights [48][1024+pad] in LDS. Per chunk: 4x
// global_load_lds into wave-private buffer, vmcnt(0), ds_read, 6 MFMA.
// h written via packed global_atomic_swap_x2 (L3-resident).
#define NBLK 256
#define STGOFF 98304                  // 48*1024*2 bytes of weights
#define LDS_BYTES 163840              // + 16 waves * 4KB staging (sG aliased)

__global__ __launch_bounds__(1024, 4) void lstm_loop(
    const bf16_t* __restrict__ whh0, const bf16_t* __restrict__ wih1,
    const bf16_t* __restrict__ whh1, const bf16_t* __restrict__ x0gT,
    const float* __restrict__ bias1, const float* __restrict__ c0in,
    bf16_t* __restrict__ h0h, bf16_t* __restrict__ h0l,     // hist [65][128][1024]
    bf16_t* __restrict__ h1h, bf16_t* __restrict__ h1l,     // hist [65][128][1024]
    float* __restrict__ outH, float* __restrict__ outC, int* bar)
{
  extern __shared__ char smem[];
  bf16_t* wlds = (bf16_t*)smem;
  float*  sG   = (float*)(smem + STGOFF);    // 4 regions x [128][17] (aliases staging)

  // one-time acquire: invalidate stale L1/L2 lines (poison / prior replay)
  __threadfence();

  const int tid = threadIdx.x, lane = tid & 63, wv = tid >> 6;
  const int l15 = lane & 15, hi4 = lane >> 4;
  const int hc0 = blockIdx.x * 4;
  const int rg = wv & 7, kh = wv >> 3;

  // ---- stage weights into LDS once (XOR slot swizzle: slot ^ (row&7)) ----
  for (int e = tid; e < 6144; e += 1024){
    int m = e >> 11, r = e & 2047, n = r >> 7, kc = r & 127;
    const bf16_t* Wm = (m == 0) ? whh0 : ((m == 1) ? wih1 : whh1);
    int row = ((n >> 2) << 10) + hc0 + (n & 3);
    bf16x8 v = *(const bf16x8*)(Wm + (size_t)row*1024 + kc*8);
    *(bf16x8*)(wlds + (size_t)(m*16 + n)*1024 + (kc ^ (n & 7))*8) = v;
  }
  __syncthreads();

  // cell mapping: threads 0..511 own 1 cell per layer
  const bool cell = (tid < 512);
  const int crow = tid >> 2, q = tid & 3;
  const size_t cellix = (size_t)crow*1024 + hc0 + q;
  float c0reg = 0.f, c1reg = 0.f, bs[4] = {};
  if (cell){
    c0reg = c0in[cellix];
    c1reg = c0in[131072 + cellix];
    #pragma unroll
    for (int g=0; g<4; ++g) bs[g] = bias1[(g<<10) + hc0 + q];
  }

  // staging geometry
  bf16_t* mybuf = (bf16_t*)(smem + STGOFF + wv*4096);     // 4 arrays x 512 elems
  const size_t srcoff = (size_t)(rg*16 + (lane >> 2))*1024
                      + (size_t)(((lane & 3) ^ ((lane >> 4) & 3)) * 8);
  const int rdoff = l15*32 + ((hi4 ^ ((l15 >> 2) & 3)) * 8);
  const int wbA = (0*16 + l15)*1024;
  const int wbB = (1*16 + l15)*1024;
  const int wbC = (2*16 + l15)*1024;

  for (int p = 0; p <= 64; ++p){
    const bf16_t* h0h_ = h0h + (size_t)p*131072;
    const bf16_t* h0l_ = h0l + (size_t)p*131072;
    const bf16_t* h1ph = h1h + (size_t)(p >= 1 ? p-1 : 0)*131072;
    const bf16_t* h1pl = h1l + (size_t)(p >= 1 ? p-1 : 0)*131072;

    // x0g loads (dense transposed layout)
    float xg[4] = {0,0,0,0};
    if (cell && p < 64){
      int bg = crow >> 4, rr = crow & 15;
      #pragma unroll
      for (int g=0; g<4; ++g)
        xg[g] = (float)x0gT[((((size_t)p*8 + bg)*4 + g)*1024 + hc0 + q)*16 + rr];
    }

    // ---- K-loop: async-staged chunks (32 K-elems each), wave-private ----
    f32x4 accA = {}, accB = {};
    #pragma unroll
    for (int c = 0; c < 16; ++c){
      const int k0 = kh*512 + c*32;
      gll16(h0h_ + srcoff + k0, mybuf + 0*512);
      gll16(h0l_ + srcoff + k0, mybuf + 1*512);
      gll16(h1ph + srcoff + k0, mybuf + 2*512);
      gll16(h1pl + srcoff + k0, mybuf + 3*512);
      asm volatile("s_waitcnt vmcnt(0)" ::: "memory");
      __builtin_amdgcn_sched_barrier(0);
      bf16x8 a0h = *(const bf16x8*)(mybuf + 0*512 + rdoff);
      bf16x8 a0l = *(const bf16x8*)(mybuf + 1*512 + rdoff);
      bf16x8 a1h = *(const bf16x8*)(mybuf + 2*512 + rdoff);
      bf16x8 a1l = *(const bf16x8*)(mybuf + 3*512 + rdoff);
      const int slot = kh*64 + c*4 + hi4;
      const int ws = (slot ^ (l15 & 7)) * 8;
      bf16x8 w0 = *(const bf16x8*)(wlds + wbA + ws);
      bf16x8 w1 = *(const bf16x8*)(wlds + wbB + ws);
      bf16x8 w2 = *(const bf16x8*)(wlds + wbC + ws);
      MFMA16(accA, a0h, w0); MFMA16(accA, a0l, w0);
      MFMA16(accB, a0h, w1); MFMA16(accB, a0l, w1);
      MFMA16(accB, a1h, w2); MFMA16(accB, a1l, w2);
    }

    // ---- staging dead; sG (aliased) becomes live ----
    __syncthreads();
    {
      const int rowb = rg*16 + hi4*4;
      #pragma unroll
      for (int r=0;r<4;r++){
        sG[(0*2 + kh)*2176 + (rowb + r)*17 + l15] = accA[r];
        sG[(2 + kh)*2176 + (rowb + r)*17 + l15]   = accB[r];
      }
    }
    __syncthreads();

    // ---- cells (packed L3-resident atomic h stores) ----
    if (cell){
      if (p < 64){
        float gv[4];
        #pragma unroll
        for (int g=0; g<4; ++g)
          gv[g] = sG[0*2176 + crow*17 + g*4 + q] + sG[1*2176 + crow*17 + g*4 + q] + xg[g];
        float cv = sigm(gv[1])*c0reg + sigm(gv[0])*tanhf(gv[2]);
        float hv = sigm(gv[3])*tanhf(cv);
        c0reg = cv;
        bf16_t hh = (bf16_t)hv;
        bf16_t hl = (bf16_t)(hv - (float)hh);
        uint32_t hu = (uint32_t)__builtin_bit_cast(uint16_t, hh);
        uint32_t lu = (uint32_t)__builtin_bit_cast(uint16_t, hl);
        uint32_t hu1 = (uint32_t)__shfl_xor((int)hu, 1);
        uint32_t lu1 = (uint32_t)__shfl_xor((int)lu, 1);
        uint32_t hp = (hu & 0xffffu) | (hu1 << 16);
        uint32_t lp = (lu & 0xffffu) | (lu1 << 16);
        uint32_t hpB = (uint32_t)__shfl_xor((int)hp, 2);
        uint32_t lpB = (uint32_t)__shfl_xor((int)lp, 2);
        if (q == 0){
          uint64_t h64 = (uint64_t)hp | ((uint64_t)hpB << 32);
          uint64_t l64 = (uint64_t)lp | ((uint64_t)lpB << 32);
          atom_sw64(h0h + (size_t)(p+1)*131072 + cellix, h64);
          atom_sw64(h0l + (size_t)(p+1)*131072 + cellix, l64);
        }
        if (p == 63){ outH[cellix] = hv; outC[cellix] = cv; }
      }
      if (p >= 1){
        float gv[4];
        #pragma unroll
        for (int g=0; g<4; ++g)
          gv[g] = sG[2*2176 + crow*17 + g*4 + q] + sG[3*2176 + crow*17 + g*4 + q] + bs[g];
        float cv = sigm(gv[1])*c1reg + sigm(gv[0])*tanhf(gv[2]);
        float hv = sigm(gv[3])*tanhf(cv);
        c1reg = cv;
        bf16_t hh = (bf16_t)hv;
        bf16_t hl = (bf16_t)(hv - (float)hh);
        uint32_t hu = (uint32_t)__builtin_bit_cast(uint16_t, hh);
        uint32_t lu = (uint32_t)__builtin_bit_cast(uint16_t, hl);
        uint32_t hu1 = (uint32_t)__shfl_xor((int)hu, 1);
        uint32_t lu1 = (uint32_t)__shfl_xor((int)lu, 1);
        uint32_t hp = (hu & 0xffffu) | (hu1 << 16);
        uint32_t lp = (lu & 0xffffu) | (lu1 << 16);
        uint32_t hpB = (uint32_t)__shfl_xor((int)hp, 2);
        uint32_t lpB = (uint32_t)__shfl_xor((int)lp, 2);
        if (q == 0){
          uint64_t h64 = (uint64_t)hp | ((uint64_t)hpB << 32);
          uint64_t l64 = (uint64_t)lp | ((uint64_t)lpB << 32);
          atom_sw64(h1h + (size_t)p*131072 + cellix, h64);
          atom_sw64(h1l + (size_t)p*131072 + cellix, l64);
        }
        if (p == 64){ outH[131072 + cellix] = hv; outC[131072 + cellix] = cv; }
      }
    }

    // ---- grid barrier (fence-free; 16 spread sub-counters) ----
    if (p < 64){
      __syncthreads();   // drains each wave's vmem (incl. atomics)
      if (tid == 0){
        __hip_atomic_fetch_add(bar + (blockIdx.x & 15)*64, 1, __ATOMIC_RELAXED, __HIP_MEMORY_SCOPE_AGENT);
        const int tgt = NBLK*(p+1);
        for(;;){
          int s = 0;
          #pragma unroll
          for (int i=0;i<16;i++)
            s += __hip_atomic_load(bar + i*64, __ATOMIC_RELAXED, __HIP_MEMORY_SCOPE_AGENT);
          if (s >= tgt) break;
          __builtin_amdgcn_s_sleep(2);
        }
      }
      __syncthreads();
      asm volatile("" ::: "memory");
      __builtin_amdgcn_sched_barrier(0);
    }
  }
}

// ---------------- scores + softmax (per batch row b), post-loop ----------------
__global__ __launch_bounds__(256) void attn_sm(
    const bf16_t* __restrict__ h1h, const bf16_t* __restrict__ h1l,
    const bf16_t* __restrict__ cwh, const bf16_t* __restrict__ cwl,
    float* __restrict__ a_all, float* __restrict__ outA)
{
  __shared__ bf16_t sAh[64*64], sAl[64*64];
  __shared__ bf16_t sBh[128*64], sBl[128*64];
  __shared__ float sS[64*128];
  int b = blockIdx.x;
  int tid = threadIdx.x, lane = tid&63, w = tid>>6;
  int wr = w>>1, wcc = w&1;
  f32x4 acc[2][4] = {};
  for (int kt=0; kt<1024; kt+=64){
    __syncthreads();
    #pragma unroll
    for (int i=0;i<2;i++){
      int c = i*256+tid; int r = c>>3, kk=(c&7)<<3;
      size_t src = (size_t)(r+1)*131072 + (size_t)b*1024 + kt+kk;
      gll16(h1h + src, sAh + (size_t)(i*256 + w*64)*8);
      gll16(h1l + src, sAl + (size_t)(i*256 + w*64)*8);
    }
    #pragma unroll
    for (int i=0;i<4;i++){
      int c = i*256+tid; int br=c>>3, kk=(c&7)<<3;
      size_t src = ((size_t)b*128 + br)*1024 + kt+kk;
      gll16(cwh + src, sBh + (size_t)(i*256+w*64)*8);
      gll16(cwl + src, sBl + (size_t)(i*256+w*64)*8);
    }
    __syncthreads();
    #pragma unroll
    for (int kk=0;kk<64;kk+=32){
      bf16x8 avh[2], avl[2], bvh[4], bvl[4];
      #pragma unroll
      for (int m=0;m<2;m++){
        int off = (wr*32 + m*16 + (lane&15))*64 + kk + ((lane>>4)<<3);
        avh[m] = *(const bf16x8*)(sAh + off);
        avl[m] = *(const bf16x8*)(sAl + off);
      }
      #pragma unroll
      for (int n=0;n<4;n++){
        int off = (wcc*64 + n*16 + (lane&15))*64 + kk + ((lane>>4)<<3);
        bvh[n] = *(const bf16x8*)(sBh + off);
        bvl[n] = *(const bf16x8*)(sBl + off);
      }
      #pragma unroll
      for (int m=0;m<2;m++)
        #pragma unroll
        for (int n=0;n<4;n++){
          acc[m][n] = __builtin_amdgcn_mfma_f32_16x16x32_bf16(avh[m], bvh[n], acc[m][n], 0,0,0);
          acc[m][n] = __builtin_amdgcn_mfma_f32_16x16x32_bf16(avl[m], bvh[n], acc[m][n], 0,0,0);
          acc[m][n] = __builtin_amdgcn_mfma_f32_16x16x32_bf16(avh[m], bvl[n], acc[m][n], 0,0,0);
        }
    }
  }
  #pragma unroll
  for (int m=0;m<2;m++)
    #pragma unroll
    for (int n=0;n<4;n++)
      #pragma unroll
      for (int r=0;r<4;r++){
        int trow = wr*32 + m*16 + ((lane>>4)<<2) + r;
        int tc   = wcc*64 + n*16 + (lane&15);
        sS[trow*128+tc] = acc[m][n][r];
      }
  __syncthreads();
  for (int i=0;i<16;i++){
    int r = w*16 + i;
    float v0 = sS[r*128 + lane], v1 = sS[r*128 + 64 + lane];
    float mx = fmaxf(v0, v1);
    #pragma unroll
    for (int off=32; off; off>>=1) mx = fmaxf(mx, __shfl_xor(mx, off));
    float e0 = expf(v0-mx), e1 = expf(v1-mx);
    float sm = e0+e1;
    #pragma unroll
    for (int off=32; off; off>>=1) sm += __shfl_xor(sm, off);
    float inv = 1.f/sm;
    size_t base = ((size_t)r*128 + b)*128;
    a_all[base + lane]      = e0*inv;
    a_all[base + 64 + lane] = e1*inv;
    if (r == 63){
      outA[(size_t)b*128 + lane]      = e0*inv;
      outA[(size_t)b*128 + 64 + lane] = e1*inv;
    }
  }
}

// ---------------- wc (fp32 VALU): wc[t,b,:] = sum_s a[t,b,s]*ctx[b,s,:] ----
__global__ __launch_bounds__(256) void wc_all(
    const float* __restrict__ a_all, const float* __restrict__ ctx,
    bf16_t* __restrict__ wch, bf16_t* __restrict__ wcl)
{
  int bid = blockIdx.x;
  int b = bid & 127, tg = bid >> 7;  // tg 0..3, 16 t each
  int tid = threadIdx.x;
  __shared__ float sa[16][128];
  int t0 = tg*16;
  #pragma unroll
  for (int i=0;i<8;i++){
    int q = i*256 + tid;
    int ti = q >> 7, s = q & 127;
    sa[ti][s] = a_all[((size_t)(t0+ti)*128 + b)*128 + s];
  }
  __syncthreads();
  f32x4 acc[16];
  #pragma unroll
  for (int i=0;i<16;i++) acc[i] = f32x4{0,0,0,0};
  const float* cb = ctx + (size_t)b*128*1024 + tid*4;
  for (int s=0;s<128;s++){
    f32x4 c = *(const f32x4*)(cb + (size_t)s*1024);
    #pragma unroll
    for (int ti=0;ti<16;ti++){
      float av = sa[ti][s];
      acc[ti] += av * c;
    }
  }
  #pragma unroll
  for (int ti=0;ti<16;ti++){
    size_t m = (size_t)(t0+ti)*128 + b;
    bf16x4 h, l;
    #pragma unroll
    for (int j=0;j<4;j++){
      float v = acc[ti][j];
      h[j] = (bf16_t)v; l[j] = (bf16_t)(v - (float)h[j]);
    }
    *(bf16x4*)(wch + m*1024 + tid*4) = h;
    *(bf16x4*)(wcl + m*1024 + tid*4) = l;
  }
}

// ---------------- host ----------------
extern "C" void kernel_launch(void* const* d_in, const int* in_sizes, int n_in,
                              void* d_out, int out_size, void* d_ws, size_t ws_size,
                              hipStream_t stream)
{
  (void)in_sizes; (void)n_in; (void)out_size; (void)ws_size;
  const int TT=64, BB=128, H=1024, G=4096, BH=128*1024;

  const int*   tok  = (const int*)d_in[0];
  const float* h0   = (const float*)d_in[1];
  const float* c0   = (const float*)d_in[2];
  const float* ctx  = (const float*)d_in[3];
  const float* embW = (const float*)d_in[5];
  const float* wih  = (const float*)d_in[6];
  const float* whh  = (const float*)d_in[7];
  const float* bih  = (const float*)d_in[8];
  const float* bhh  = (const float*)d_in[9];
  const float* Win  = (const float*)d_in[10];
  const float* Wout = (const float*)d_in[11];

  float* outY = (float*)d_out;                      // [T,B,H]
  float* outH = outY + (size_t)TT*BB*H;             // [2,B,H]
  float* outC = outH + (size_t)2*BH;                // [2,B,H]
  float* outA = outC + (size_t)2*BH;                // [B,S]

  char* ws = (char*)d_ws;
  size_t o = 0;
  auto carve = [&](size_t bytes)->char* {
    char* p = ws + o; o += (bytes + 255) & ~(size_t)255; return p;
  };
  bf16_t* wihB  = (bf16_t*)carve((size_t)2*G*H*2);       // 16MB
  bf16_t* whhB  = (bf16_t*)carve((size_t)2*G*H*2);       // 16MB
  bf16_t* woutH = (bf16_t*)carve((size_t)H*2*H*2);       // 4MB
  bf16_t* woutL = (bf16_t*)carve((size_t)H*2*H*2);       // 4MB
  bf16_t* winTh = (bf16_t*)carve((size_t)H*H*2);         // 2MB
  bf16_t* winTl = (bf16_t*)carve((size_t)H*H*2);         // 2MB
  bf16_t* ctxh  = (bf16_t*)carve((size_t)BB*128*H*2);    // 32MB; loop: h0 hist hi; post: wch
  bf16_t* ctxl  = (bf16_t*)carve((size_t)BB*128*H*2);    // 32MB; loop: h0 hist lo; post: wcl
  bf16_t* cwh   = (bf16_t*)carve((size_t)BB*128*H*2);    // 32MB (pre: xemb overlays)
  bf16_t* cwl   = (bf16_t*)carve((size_t)BB*128*H*2);    // 32MB
  bf16_t* x0gT  = (bf16_t*)carve((size_t)TT*BB*G*2);     // 64MB
  bf16_t* h1h   = (bf16_t*)carve((size_t)(TT+1)*BH*2);   // 17MB history
  bf16_t* h1l   = (bf16_t*)carve((size_t)(TT+1)*BH*2);   // 17MB
  float*  a_all = (float*)carve((size_t)TT*BB*128*4);    // 4MB
  float*  biasF = (float*)carve((size_t)2*G*4);
  int*    bar   = (int*)carve(16*64*4);

  bf16_t* xemb   = cwh;          // overlays ctxW-hi (dead until ctxW GEMM)
  bf16_t* h0hist = ctxh;         // h0 history [65][128][1024] (ctx dead after ctxW GEMM)
  bf16_t* h0histl= ctxl;
  bf16_t* wch    = ctxh;         // post-loop overlay (h0 hist dead then)
  bf16_t* wcl    = ctxl;

  // ---- prep ----
  hipMemsetAsync(bar, 0, 16*64*4, stream);
  f2b<<<(2*G*H)/1024, 256, 0, stream>>>(wih, wihB, 2*G*H);
  f2b<<<(2*G*H)/1024, 256, 0, stream>>>(whh, whhB, 2*G*H);
  f2b_pair<<<(H*2*H)/1024, 256, 0, stream>>>(Wout, woutH, woutL, H*2*H);
  f2b_pair<<<(BB*128*H)/1024, 256, 0, stream>>>(ctx, ctxh, ctxl, BB*128*H);
  f2b_pair<<<BH/1024, 256, 0, stream>>>(h0 + BH, h1h, h1l, BH);
  transWin<<<1024, 256, 0, stream>>>(Win, winTh, winTl);
  bias_combine<<<(2*G)/256, 256, 0, stream>>>(bih, bhh, biasF, 2*G);
  embed_gather<<<TT*BB, 256, 0, stream>>>(tok, embW, xemb);

  // ---- one-time GEMMs ----
  gemm_bt<<<(TT*BB/128)*(G/128), 256, 0, stream>>>(xemb, wihB, biasF, x0gT, TT*BB, G, H, G/128);
  gemm_split<0,1><<<(BB*128/128)*(H/128), 256, 0, stream>>>(
      ctxh, ctxl, ctxh, ctxl, H, winTh, winTl,
      nullptr, cwh, cwl, BB*128, H, H, H/128);

  // h0 layer-0 initial state -> h0 history slot 0 (ctx region now dead)
  f2b_pair<<<BH/1024, 256, 0, stream>>>(h0, h0hist, h0histl, BH);

  // ---- persistent recurrence ----
  hipFuncSetAttribute((const void*)lstm_loop,
                      hipFuncAttributeMaxDynamicSharedMemorySize, LDS_BYTES);
  lstm_loop<<<NBLK, 1024, LDS_BYTES, stream>>>(
      whhB, wihB + (size_t)G*H, whhB + (size_t)G*H, x0gT, biasF + G, c0,
      h0hist, h0histl, h1h, h1l, outH, outC, bar);

  // ---- post-loop attention ----
  attn_sm<<<BB, 256, 0, stream>>>(h1h, h1l, cwh, cwl, a_all, outA);
  wc_all<<<BB*4, 256, 0, stream>>>(a_all, ctx, wch, wcl);

  gemm_split<1,0><<<(TT*BB/128)*(H/128), 256, 0, stream>>>(
      wch, wcl, h1h + BH, h1l + BH, H, woutH, woutL,
      outY, nullptr, nullptr, TT*BB, H, 2*H, H/128);
}

// Round 18
// 1961.562 us; speedup vs baseline: 1.4498x; 1.1525x over previous
//
#include <hip/hip_runtime.h>
#include <hip/hip_bf16.h>
#include <stdint.h>

// Decoder: 2-layer LSTM + Luong attention. input_feed=0 => attention deferred
// post-loop. R18 = R12/R14 best-known config (weights in LDS, 16 waves,
// async gll16 h staging, sc0sc1 write-through h stores) + hierarchical
// barrier: blocks signal 16 spread counters; block 0 aggregates and
// publishes a single done-flag; all others poll ONE location.

typedef __bf16 bf16_t;
typedef __bf16 bf16x8 __attribute__((ext_vector_type(8)));
typedef __bf16 bf16x4 __attribute__((ext_vector_type(4)));
typedef float f32x4 __attribute__((ext_vector_type(4)));

#define AS1 __attribute__((address_space(1)))
#define AS3 __attribute__((address_space(3)))

__device__ __forceinline__ void gll16(const bf16_t* g, bf16_t* l) {
  __builtin_amdgcn_global_load_lds((const AS1 void*)g, (AS3 void*)l, 16, 0, 0);
}

__device__ __forceinline__ float sigm(float x){ return 1.f/(1.f+expf(-x)); }

#define MFMA16(acc, a, b) acc = __builtin_amdgcn_mfma_f32_16x16x32_bf16(a, b, acc, 0,0,0)

// system write-through coherent store (proven R5/R8/R12/R14)
__device__ __forceinline__ void stg_sc(bf16_t* p, bf16_t v){
  uint32_t w = (uint32_t)__builtin_bit_cast(uint16_t, v);
  asm volatile("global_store_short %0, %1, off sc0 sc1" :: "v"(p), "v"(w) : "memory");
}

// ---------------- prep kernels ----------------
__global__ void f2b(const float* __restrict__ in, bf16_t* __restrict__ outp, int n){
  int i = (blockIdx.x*256 + threadIdx.x)*4;
  if (i >= n) return;
  float4 v = *(const float4*)(in + i);
  bf16x4 o; o[0]=(bf16_t)v.x; o[1]=(bf16_t)v.y; o[2]=(bf16_t)v.z; o[3]=(bf16_t)v.w;
  *(bf16x4*)(outp + i) = o;
}

__global__ void f2b_pair(const float* __restrict__ in, bf16_t* __restrict__ oh,
                         bf16_t* __restrict__ ol, int n){
  int i = (blockIdx.x*256 + threadIdx.x)*4;
  if (i >= n) return;
  float4 v = *(const float4*)(in + i);
  float vv[4] = {v.x, v.y, v.z, v.w};
  bf16x4 h, l;
  #pragma unroll
  for (int j=0;j<4;j++){ h[j]=(bf16_t)vv[j]; l[j]=(bf16_t)(vv[j]-(float)h[j]); }
  *(bf16x4*)(oh + i) = h;
  *(bf16x4*)(ol + i) = l;
}

__global__ void bias_combine(const float* __restrict__ a, const float* __restrict__ b,
                             float* __restrict__ o, int n){
  int i = blockIdx.x*256 + threadIdx.x;
  if (i < n) o[i] = a[i] + b[i];
}

__global__ void embed_gather(const int* __restrict__ tokp, const float* __restrict__ embW,
                             bf16_t* __restrict__ xe){
  int m = blockIdx.x;
  int tokv = tokp[m];
  const float* src = embW + (size_t)tokv*1024 + threadIdx.x*4;
  float4 v = *(const float4*)src;
  bf16x4 o; o[0]=(bf16_t)v.x; o[1]=(bf16_t)v.y; o[2]=(bf16_t)v.z; o[3]=(bf16_t)v.w;
  *(bf16x4*)(xe + (size_t)m*1024 + threadIdx.x*4) = o;
}

// winT[e,d] = split(Win[d,e])
__global__ void transWin(const float* __restrict__ in, bf16_t* __restrict__ oh,
                         bf16_t* __restrict__ ol){
  __shared__ float t[32][33];
  int bi = blockIdx.x & 31, bj = blockIdx.x >> 5;
  int tx = threadIdx.x & 31, ty = threadIdx.x >> 5;  // 32 x 8
  #pragma unroll
  for (int i=0;i<4;i++){
    int d = bi*32 + ty + i*8, e = bj*32 + tx;
    t[ty+i*8][tx] = in[(size_t)d*1024 + e];
  }
  __syncthreads();
  #pragma unroll
  for (int i=0;i<4;i++){
    int e = bj*32 + ty + i*8, d = bi*32 + tx;
    float v = t[tx][ty+i*8];
    bf16_t h = (bf16_t)v;
    oh[(size_t)e*1024 + d] = h;
    ol[(size_t)e*1024 + d] = (bf16_t)(v - (float)h);
  }
}

// -------- x0g GEMM: x0gT[t][bg][g][col][16 rows] = xemb@wih0^T + bias0 --------
__global__ __launch_bounds__(256) void gemm_bt(
    const bf16_t* __restrict__ A, const bf16_t* __restrict__ Bm,
    const float* __restrict__ bias, bf16_t* __restrict__ Cout,
    int M, int N, int K, int nTN)
{
  __shared__ bf16_t sA[128*64];
  __shared__ bf16_t sB[128*64];
  int tid = threadIdx.x, lane = tid & 63, w = tid >> 6;
  int tm = blockIdx.x / nTN, tn = blockIdx.x % nTN;
  int row0 = tm*128, col0 = tn*128;
  int wr = w >> 1, wcc = w & 1;
  f32x4 acc[4][4] = {};
  for (int kt = 0; kt < K; kt += 64) {
    __syncthreads();
    #pragma unroll
    for (int i=0;i<4;i++){
      int c = i*256 + tid;
      int r = c >> 3, kk = (c & 7) << 3;
      gll16(A  + (size_t)(row0+r)*K + kt + kk, sA + (size_t)(i*256 + w*64)*8);
      gll16(Bm + (size_t)(col0+r)*K + kt + kk, sB + (size_t)(i*256 + w*64)*8);
    }
    __syncthreads();
    #pragma unroll
    for (int kk=0;kk<64;kk+=32){
      bf16x8 av[4], bv[4];
      #pragma unroll
      for (int m=0;m<4;m++) av[m] = *(const bf16x8*)(sA + (wr*64 + m*16 + (lane&15))*64 + kk + ((lane>>4)<<3));
      #pragma unroll
      for (int n=0;n<4;n++) bv[n] = *(const bf16x8*)(sB + (wcc*64 + n*16 + (lane&15))*64 + kk + ((lane>>4)<<3));
      #pragma unroll
      for (int m=0;m<4;m++)
        #pragma unroll
        for (int n=0;n<4;n++)
          acc[m][n] = __builtin_amdgcn_mfma_f32_16x16x32_bf16(av[m], bv[n], acc[m][n], 0,0,0);
    }
  }
  #pragma unroll
  for (int n=0;n<4;n++){
    int cn = col0 + wcc*64 + n*16 + (lane & 15);
    float bvv = bias[cn];
    int g = cn >> 10, col = cn & 1023;
    #pragma unroll
    for (int m=0;m<4;m++){
      int rm = row0 + wr*64 + m*16 + ((lane>>4)<<2);
      int p = rm >> 7, bgi = (rm >> 4) & 7, rr = rm & 15;
      bf16x4 o;
      #pragma unroll
      for (int r=0;r<4;r++) o[r] = (bf16_t)(acc[m][n][r] + bvv);
      *(bf16x4*)(Cout + ((((size_t)p*8+bgi)*4+g)*1024 + col)*16 + rr) = o;
    }
  }
}

// ---------------- split GEMM: hi/lo A (two K-parts) x hi/lo B, 3 combos ----------------
template<int ACT_TANH, int OUT_PAIR>
__global__ __launch_bounds__(256) void gemm_split(
    const bf16_t* __restrict__ Ah1, const bf16_t* __restrict__ Al1,
    const bf16_t* __restrict__ Ah2, const bf16_t* __restrict__ Al2, int K1,
    const bf16_t* __restrict__ Bh, const bf16_t* __restrict__ Bl,
    float* __restrict__ Cf, bf16_t* __restrict__ Ch, bf16_t* __restrict__ Cl,
    int M, int N, int K, int nTN)
{
  __shared__ bf16_t sAh[128*64], sAl[128*64], sBh[128*64], sBl[128*64];
  int tid = threadIdx.x, lane = tid & 63, w = tid >> 6;
  int tm = blockIdx.x / nTN, tn = blockIdx.x % nTN;
  int row0 = tm*128, col0 = tn*128;
  int wr = w >> 1, wcc = w & 1;
  f32x4 acc[4][4] = {};
  for (int kt = 0; kt < K; kt += 64) {
    const bf16_t *Ah, *Al; int kl;
    if (kt < K1){ Ah=Ah1; Al=Al1; kl=kt; } else { Ah=Ah2; Al=Al2; kl=kt-K1; }
    __syncthreads();
    #pragma unroll
    for (int i=0;i<4;i++){
      int c = i*256 + tid;
      int r = c >> 3, kk = (c & 7) << 3;
      gll16(Ah + (size_t)(row0+r)*K1 + kl + kk, sAh + (size_t)(i*256 + w*64)*8);
      gll16(Al + (size_t)(row0+r)*K1 + kl + kk, sAl + (size_t)(i*256 + w*64)*8);
      gll16(Bh + (size_t)(col0+r)*K + kt + kk, sBh + (size_t)(i*256 + w*64)*8);
      gll16(Bl + (size_t)(col0+r)*K + kt + kk, sBl + (size_t)(i*256 + w*64)*8);
    }
    __syncthreads();
    #pragma unroll
    for (int kk=0;kk<64;kk+=32){
      bf16x8 avh[4], avl[4], bvh[4], bvl[4];
      #pragma unroll
      for (int m=0;m<4;m++){
        int off = (wr*64 + m*16 + (lane&15))*64 + kk + ((lane>>4)<<3);
        avh[m] = *(const bf16x8*)(sAh + off);
        avl[m] = *(const bf16x8*)(sAl + off);
      }
      #pragma unroll
      for (int n=0;n<4;n++){
        int off = (wcc*64 + n*16 + (lane&15))*64 + kk + ((lane>>4)<<3);
        bvh[n] = *(const bf16x8*)(sBh + off);
        bvl[n] = *(const bf16x8*)(sBl + off);
      }
      #pragma unroll
      for (int m=0;m<4;m++)
        #pragma unroll
        for (int n=0;n<4;n++){
          acc[m][n] = __builtin_amdgcn_mfma_f32_16x16x32_bf16(avh[m], bvh[n], acc[m][n], 0,0,0);
          acc[m][n] = __builtin_amdgcn_mfma_f32_16x16x32_bf16(avl[m], bvh[n], acc[m][n], 0,0,0);
          acc[m][n] = __builtin_amdgcn_mfma_f32_16x16x32_bf16(avh[m], bvl[n], acc[m][n], 0,0,0);
        }
    }
  }
  #pragma unroll
  for (int n=0;n<4;n++){
    int cn = col0 + wcc*64 + n*16 + (lane & 15);
    #pragma unroll
    for (int m=0;m<4;m++){
      int rm = row0 + wr*64 + m*16 + ((lane>>4)<<2);
      #pragma unroll
      for (int r=0;r<4;r++){
        float v = acc[m][n][r];
        if (ACT_TANH) v = tanhf(v);
        if (OUT_PAIR){
          bf16_t h = (bf16_t)v;
          Ch[(size_t)(rm+r)*N + cn] = h;
          Cl[(size_t)(rm+r)*N + cn] = (bf16_t)(v - (float)h);
        } else {
          Cf[(size_t)(rm+r)*N + cn] = v;
        }
      }
    }
  }
}

// ---------------- persistent LSTM loop: weights in LDS, async h staging ----------------
// 256 blocks x 1024 thr (16 waves = 8 row-groups rg x 2 K-halves kh).
#define NBLK 256
#define STGOFF 98304                  // 48*1024*2 bytes of weights
#define LDS_BYTES 163840              // + 16 waves * 4KB staging (sG aliased)

__global__ __launch_bounds__(1024, 4) void lstm_loop(
    const bf16_t* __restrict__ whh0, const bf16_t* __restrict__ wih1,
    const bf16_t* __restrict__ whh1, const bf16_t* __restrict__ x0gT,
    const float* __restrict__ bias1, const float* __restrict__ c0in,
    bf16_t* __restrict__ h0h, bf16_t* __restrict__ h0l,     // hist [65][128][1024]
    bf16_t* __restrict__ h1h, bf16_t* __restrict__ h1l,     // hist [65][128][1024]
    float* __restrict__ outH, float* __restrict__ outC, int* bar, int* done)
{
  extern __shared__ char smem[];
  bf16_t* wlds = (bf16_t*)smem;
  float*  sG   = (float*)(smem + STGOFF);    // 4 regions x [128][17] (aliases staging)

  // one-time acquire: invalidate stale L1/L2 lines (poison / prior replay)
  __threadfence();

  const int tid = threadIdx.x, lane = tid & 63, wv = tid >> 6;
  const int l15 = lane & 15, hi4 = lane >> 4;
  const int hc0 = blockIdx.x * 4;
  const int rg = wv & 7, kh = wv >> 3;

  // ---- stage weights into LDS once (XOR slot swizzle: slot ^ (row&7)) ----
  for (int e = tid; e < 6144; e += 1024){
    int m = e >> 11, r = e & 2047, n = r >> 7, kc = r & 127;
    const bf16_t* Wm = (m == 0) ? whh0 : ((m == 1) ? wih1 : whh1);
    int row = ((n >> 2) << 10) + hc0 + (n & 3);
    bf16x8 v = *(const bf16x8*)(Wm + (size_t)row*1024 + kc*8);
    *(bf16x8*)(wlds + (size_t)(m*16 + n)*1024 + (kc ^ (n & 7))*8) = v;
  }
  __syncthreads();

  // cell mapping: threads 0..511 own 1 cell per layer
  const bool cell = (tid < 512);
  const int crow = tid >> 2, q = tid & 3;
  const size_t cellix = (size_t)crow*1024 + hc0 + q;
  float c0reg = 0.f, c1reg = 0.f, bs[4] = {};
  if (cell){
    c0reg = c0in[cellix];
    c1reg = c0in[131072 + cellix];
    #pragma unroll
    for (int g=0; g<4; ++g) bs[g] = bias1[(g<<10) + hc0 + q];
  }

  // staging geometry
  bf16_t* mybuf = (bf16_t*)(smem + STGOFF + wv*4096);     // 4 arrays x 512 elems
  const size_t srcoff = (size_t)(rg*16 + (lane >> 2))*1024
                      + (size_t)(((lane & 3) ^ ((lane >> 4) & 3)) * 8);
  const int rdoff = l15*32 + ((hi4 ^ ((l15 >> 2) & 3)) * 8);
  const int wbA = (0*16 + l15)*1024;
  const int wbB = (1*16 + l15)*1024;
  const int wbC = (2*16 + l15)*1024;

  for (int p = 0; p <= 64; ++p){
    const bf16_t* h0h_ = h0h + (size_t)p*131072;
    const bf16_t* h0l_ = h0l + (size_t)p*131072;
    const bf16_t* h1ph = h1h + (size_t)(p >= 1 ? p-1 : 0)*131072;
    const bf16_t* h1pl = h1l + (size_t)(p >= 1 ? p-1 : 0)*131072;

    // x0g loads (dense transposed layout)
    float xg[4] = {0,0,0,0};
    if (cell && p < 64){
      int bg = crow >> 4, rr = crow & 15;
      #pragma unroll
      for (int g=0; g<4; ++g)
        xg[g] = (float)x0gT[((((size_t)p*8 + bg)*4 + g)*1024 + hc0 + q)*16 + rr];
    }

    // ---- K-loop: async-staged chunks (32 K-elems each), wave-private ----
    f32x4 accA = {}, accB = {};
    #pragma unroll
    for (int c = 0; c < 16; ++c){
      const int k0 = kh*512 + c*32;
      gll16(h0h_ + srcoff + k0, mybuf + 0*512);
      gll16(h0l_ + srcoff + k0, mybuf + 1*512);
      gll16(h1ph + srcoff + k0, mybuf + 2*512);
      gll16(h1pl + srcoff + k0, mybuf + 3*512);
      asm volatile("s_waitcnt vmcnt(0)" ::: "memory");
      __builtin_amdgcn_sched_barrier(0);
      bf16x8 a0h = *(const bf16x8*)(mybuf + 0*512 + rdoff);
      bf16x8 a0l = *(const bf16x8*)(mybuf + 1*512 + rdoff);
      bf16x8 a1h = *(const bf16x8*)(mybuf + 2*512 + rdoff);
      bf16x8 a1l = *(const bf16x8*)(mybuf + 3*512 + rdoff);
      const int slot = kh*64 + c*4 + hi4;
      const int ws = (slot ^ (l15 & 7)) * 8;
      bf16x8 w0 = *(const bf16x8*)(wlds + wbA + ws);
      bf16x8 w1 = *(const bf16x8*)(wlds + wbB + ws);
      bf16x8 w2 = *(const bf16x8*)(wlds + wbC + ws);
      MFMA16(accA, a0h, w0); MFMA16(accA, a0l, w0);
      MFMA16(accB, a0h, w1); MFMA16(accB, a0l, w1);
      MFMA16(accB, a1h, w2); MFMA16(accB, a1l, w2);
    }

    // ---- staging dead; sG (aliased) becomes live ----
    __syncthreads();
    {
      const int rowb = rg*16 + hi4*4;
      #pragma unroll
      for (int r=0;r<4;r++){
        sG[(0*2 + kh)*2176 + (rowb + r)*17 + l15] = accA[r];
        sG[(2 + kh)*2176 + (rowb + r)*17 + l15]   = accB[r];
      }
    }
    __syncthreads();

    // ---- cells ----
    if (cell){
      if (p < 64){
        float gv[4];
        #pragma unroll
        for (int g=0; g<4; ++g)
          gv[g] = sG[0*2176 + crow*17 + g*4 + q] + sG[1*2176 + crow*17 + g*4 + q] + xg[g];
        float cv = sigm(gv[1])*c0reg + sigm(gv[0])*tanhf(gv[2]);
        float hv = sigm(gv[3])*tanhf(cv);
        c0reg = cv;
        bf16_t hh = (bf16_t)hv;
        stg_sc(h0h + (size_t)(p+1)*131072 + cellix, hh);
        stg_sc(h0l + (size_t)(p+1)*131072 + cellix, (bf16_t)(hv - (float)hh));
        if (p == 63){ outH[cellix] = hv; outC[cellix] = cv; }
      }
      if (p >= 1){
        float gv[4];
        #pragma unroll
        for (int g=0; g<4; ++g)
          gv[g] = sG[2*2176 + crow*17 + g*4 + q] + sG[3*2176 + crow*17 + g*4 + q] + bs[g];
        float cv = sigm(gv[1])*c1reg + sigm(gv[0])*tanhf(gv[2]);
        float hv = sigm(gv[3])*tanhf(cv);
        c1reg = cv;
        bf16_t hh = (bf16_t)hv;
        stg_sc(h1h + (size_t)p*131072 + cellix, hh);
        stg_sc(h1l + (size_t)p*131072 + cellix, (bf16_t)(hv - (float)hh));
        if (p == 64){ outH[131072 + cellix] = hv; outC[131072 + cellix] = cv; }
      }
    }

    // ---- hierarchical grid barrier: spread signal, single-flag poll ----
    if (p < 64){
      __syncthreads();   // drains each wave's vmem (incl. sc stores)
      if (tid == 0){
        __hip_atomic_fetch_add(bar + (blockIdx.x & 15)*64, 1, __ATOMIC_RELAXED, __HIP_MEMORY_SCOPE_AGENT);
        if (blockIdx.x == 0){
          const int tgt = NBLK*(p+1);
          for(;;){
            int s = 0;
            #pragma unroll
            for (int i=0;i<16;i++)
              s += __hip_atomic_load(bar + i*64, __ATOMIC_RELAXED, __HIP_MEMORY_SCOPE_AGENT);
            if (s >= tgt) break;
            __builtin_amdgcn_s_sleep(1);
          }
          __hip_atomic_store(done, p+1, __ATOMIC_RELAXED, __HIP_MEMORY_SCOPE_AGENT);
        } else {
          while (__hip_atomic_load(done, __ATOMIC_RELAXED, __HIP_MEMORY_SCOPE_AGENT) < p+1)
            __builtin_amdgcn_s_sleep(1);
        }
      }
      __syncthreads();
      asm volatile("" ::: "memory");
      __builtin_amdgcn_sched_barrier(0);
    }
  }
}

// ---------------- scores + softmax (per batch row b), post-loop ----------------
__global__ __launch_bounds__(256) void attn_sm(
    const bf16_t* __restrict__ h1h, const bf16_t* __restrict__ h1l,
    const bf16_t* __restrict__ cwh, const bf16_t* __restrict__ cwl,
    float* __restrict__ a_all, float* __restrict__ outA)
{
  __shared__ bf16_t sAh[64*64], sAl[64*64];
  __shared__ bf16_t sBh[128*64], sBl[128*64];
  __shared__ float sS[64*128];
  int b = blockIdx.x;
  int tid = threadIdx.x, lane = tid&63, w = tid>>6;
  int wr = w>>1, wcc = w&1;
  f32x4 acc[2][4] = {};
  for (int kt=0; kt<1024; kt+=64){
    __syncthreads();
    #pragma unroll
    for (int i=0;i<2;i++){
      int c = i*256+tid; int r = c>>3, kk=(c&7)<<3;
      size_t src = (size_t)(r+1)*131072 + (size_t)b*1024 + kt+kk;
      gll16(h1h + src, sAh + (size_t)(i*256 + w*64)*8);
      gll16(h1l + src, sAl + (size_t)(i*256 + w*64)*8);
    }
    #pragma unroll
    for (int i=0;i<4;i++){
      int c = i*256+tid; int br=c>>3, kk=(c&7)<<3;
      size_t src = ((size_t)b*128 + br)*1024 + kt+kk;
      gll16(cwh + src, sBh + (size_t)(i*256+w*64)*8);
      gll16(cwl + src, sBl + (size_t)(i*256+w*64)*8);
    }
    __syncthreads();
    #pragma unroll
    for (int kk=0;kk<64;kk+=32){
      bf16x8 avh[2], avl[2], bvh[4], bvl[4];
      #pragma unroll
      for (int m=0;m<2;m++){
        int off = (wr*32 + m*16 + (lane&15))*64 + kk + ((lane>>4)<<3);
        avh[m] = *(const bf16x8*)(sAh + off);
        avl[m] = *(const bf16x8*)(sAl + off);
      }
      #pragma unroll
      for (int n=0;n<4;n++){
        int off = (wcc*64 + n*16 + (lane&15))*64 + kk + ((lane>>4)<<3);
        bvh[n] = *(const bf16x8*)(sBh + off);
        bvl[n] = *(const bf16x8*)(sBl + off);
      }
      #pragma unroll
      for (int m=0;m<2;m++)
        #pragma unroll
        for (int n=0;n<4;n++){
          acc[m][n] = __builtin_amdgcn_mfma_f32_16x16x32_bf16(avh[m], bvh[n], acc[m][n], 0,0,0);
          acc[m][n] = __builtin_amdgcn_mfma_f32_16x16x32_bf16(avl[m], bvh[n], acc[m][n], 0,0,0);
          acc[m][n] = __builtin_amdgcn_mfma_f32_16x16x32_bf16(avh[m], bvl[n], acc[m][n], 0,0,0);
        }
    }
  }
  #pragma unroll
  for (int m=0;m<2;m++)
    #pragma unroll
    for (int n=0;n<4;n++)
      #pragma unroll
      for (int r=0;r<4;r++){
        int trow = wr*32 + m*16 + ((lane>>4)<<2) + r;
        int tc   = wcc*64 + n*16 + (lane&15);
        sS[trow*128+tc] = acc[m][n][r];
      }
  __syncthreads();
  for (int i=0;i<16;i++){
    int r = w*16 + i;
    float v0 = sS[r*128 + lane], v1 = sS[r*128 + 64 + lane];
    float mx = fmaxf(v0, v1);
    #pragma unroll
    for (int off=32; off; off>>=1) mx = fmaxf(mx, __shfl_xor(mx, off));
    float e0 = expf(v0-mx), e1 = expf(v1-mx);
    float sm = e0+e1;
    #pragma unroll
    for (int off=32; off; off>>=1) sm += __shfl_xor(sm, off);
    float inv = 1.f/sm;
    size_t base = ((size_t)r*128 + b)*128;
    a_all[base + lane]      = e0*inv;
    a_all[base + 64 + lane] = e1*inv;
    if (r == 63){
      outA[(size_t)b*128 + lane]      = e0*inv;
      outA[(size_t)b*128 + 64 + lane] = e1*inv;
    }
  }
}

// ---------------- wc (fp32 VALU): wc[t,b,:] = sum_s a[t,b,s]*ctx[b,s,:] ----
__global__ __launch_bounds__(256) void wc_all(
    const float* __restrict__ a_all, const float* __restrict__ ctx,
    bf16_t* __restrict__ wch, bf16_t* __restrict__ wcl)
{
  int bid = blockIdx.x;
  int b = bid & 127, tg = bid >> 7;  // tg 0..3, 16 t each
  int tid = threadIdx.x;
  __shared__ float sa[16][128];
  int t0 = tg*16;
  #pragma unroll
  for (int i=0;i<8;i++){
    int q = i*256 + tid;
    int ti = q >> 7, s = q & 127;
    sa[ti][s] = a_all[((size_t)(t0+ti)*128 + b)*128 + s];
  }
  __syncthreads();
  f32x4 acc[16];
  #pragma unroll
  for (int i=0;i<16;i++) acc[i] = f32x4{0,0,0,0};
  const float* cb = ctx + (size_t)b*128*1024 + tid*4;
  for (int s=0;s<128;s++){
    f32x4 c = *(const f32x4*)(cb + (size_t)s*1024);
    #pragma unroll
    for (int ti=0;ti<16;ti++){
      float av = sa[ti][s];
      acc[ti] += av * c;
    }
  }
  #pragma unroll
  for (int ti=0;ti<16;ti++){
    size_t m = (size_t)(t0+ti)*128 + b;
    bf16x4 h, l;
    #pragma unroll
    for (int j=0;j<4;j++){
      float v = acc[ti][j];
      h[j] = (bf16_t)v; l[j] = (bf16_t)(v - (float)h[j]);
    }
    *(bf16x4*)(wch + m*1024 + tid*4) = h;
    *(bf16x4*)(wcl + m*1024 + tid*4) = l;
  }
}

// ---------------- host ----------------
extern "C" void kernel_launch(void* const* d_in, const int* in_sizes, int n_in,
                              void* d_out, int out_size, void* d_ws, size_t ws_size,
                              hipStream_t stream)
{
  (void)in_sizes; (void)n_in; (void)out_size; (void)ws_size;
  const int TT=64, BB=128, H=1024, G=4096, BH=128*1024;

  const int*   tok  = (const int*)d_in[0];
  const float* h0   = (const float*)d_in[1];
  const float* c0   = (const float*)d_in[2];
  const float* ctx  = (const float*)d_in[3];
  const float* embW = (const float*)d_in[5];
  const float* wih  = (const float*)d_in[6];
  const float* whh  = (const float*)d_in[7];
  const float* bih  = (const float*)d_in[8];
  const float* bhh  = (const float*)d_in[9];
  const float* Win  = (const float*)d_in[10];
  const float* Wout = (const float*)d_in[11];

  float* outY = (float*)d_out;                      // [T,B,H]
  float* outH = outY + (size_t)TT*BB*H;             // [2,B,H]
  float* outC = outH + (size_t)2*BH;                // [2,B,H]
  float* outA = outC + (size_t)2*BH;                // [B,S]

  char* ws = (char*)d_ws;
  size_t o = 0;
  auto carve = [&](size_t bytes)->char* {
    char* p = ws + o; o += (bytes + 255) & ~(size_t)255; return p;
  };
  bf16_t* wihB  = (bf16_t*)carve((size_t)2*G*H*2);       // 16MB
  bf16_t* whhB  = (bf16_t*)carve((size_t)2*G*H*2);       // 16MB
  bf16_t* woutH = (bf16_t*)carve((size_t)H*2*H*2);       // 4MB
  bf16_t* woutL = (bf16_t*)carve((size_t)H*2*H*2);       // 4MB
  bf16_t* winTh = (bf16_t*)carve((size_t)H*H*2);         // 2MB
  bf16_t* winTl = (bf16_t*)carve((size_t)H*H*2);         // 2MB
  bf16_t* ctxh  = (bf16_t*)carve((size_t)BB*128*H*2);    // 32MB; loop: h0 hist hi; post: wch
  bf16_t* ctxl  = (bf16_t*)carve((size_t)BB*128*H*2);    // 32MB; loop: h0 hist lo; post: wcl
  bf16_t* cwh   = (bf16_t*)carve((size_t)BB*128*H*2);    // 32MB (pre: xemb overlays)
  bf16_t* cwl   = (bf16_t*)carve((size_t)BB*128*H*2);    // 32MB
  bf16_t* x0gT  = (bf16_t*)carve((size_t)TT*BB*G*2);     // 64MB
  bf16_t* h1h   = (bf16_t*)carve((size_t)(TT+1)*BH*2);   // 17MB history
  bf16_t* h1l   = (bf16_t*)carve((size_t)(TT+1)*BH*2);   // 17MB
  float*  a_all = (float*)carve((size_t)TT*BB*128*4);    // 4MB
  float*  biasF = (float*)carve((size_t)2*G*4);
  int*    bar   = (int*)carve(16*64*4);
  int*    done  = (int*)carve(256);

  bf16_t* xemb   = cwh;          // overlays ctxW-hi (dead until ctxW GEMM)
  bf16_t* h0hist = ctxh;         // h0 history [65][128][1024] (ctx dead after ctxW GEMM)
  bf16_t* h0histl= ctxl;
  bf16_t* wch    = ctxh;         // post-loop overlay (h0 hist dead then)
  bf16_t* wcl    = ctxl;

  // ---- prep ----
  hipMemsetAsync(bar, 0, 16*64*4, stream);
  hipMemsetAsync(done, 0, 256, stream);
  f2b<<<(2*G*H)/1024, 256, 0, stream>>>(wih, wihB, 2*G*H);
  f2b<<<(2*G*H)/1024, 256, 0, stream>>>(whh, whhB, 2*G*H);
  f2b_pair<<<(H*2*H)/1024, 256, 0, stream>>>(Wout, woutH, woutL, H*2*H);
  f2b_pair<<<(BB*128*H)/1024, 256, 0, stream>>>(ctx, ctxh, ctxl, BB*128*H);
  f2b_pair<<<BH/1024, 256, 0, stream>>>(h0 + BH, h1h, h1l, BH);
  transWin<<<1024, 256, 0, stream>>>(Win, winTh, winTl);
  bias_combine<<<(2*G)/256, 256, 0, stream>>>(bih, bhh, biasF, 2*G);
  embed_gather<<<TT*BB, 256, 0, stream>>>(tok, embW, xemb);

  // ---- one-time GEMMs ----
  gemm_bt<<<(TT*BB/128)*(G/128), 256, 0, stream>>>(xemb, wihB, biasF, x0gT, TT*BB, G, H, G/128);
  gemm_split<0,1><<<(BB*128/128)*(H/128), 256, 0, stream>>>(
      ctxh, ctxl, ctxh, ctxl, H, winTh, winTl,
      nullptr, cwh, cwl, BB*128, H, H, H/128);

  // h0 layer-0 initial state -> h0 history slot 0 (ctx region now dead)
  f2b_pair<<<BH/1024, 256, 0, stream>>>(h0, h0hist, h0histl, BH);

  // ---- persistent recurrence ----
  hipFuncSetAttribute((const void*)lstm_loop,
                      hipFuncAttributeMaxDynamicSharedMemorySize, LDS_BYTES);
  lstm_loop<<<NBLK, 1024, LDS_BYTES, stream>>>(
      whhB, wihB + (size_t)G*H, whhB + (size_t)G*H, x0gT, biasF + G, c0,
      h0hist, h0histl, h1h, h1l, outH, outC, bar, done);

  // ---- post-loop attention ----
  attn_sm<<<BB, 256, 0, stream>>>(h1h, h1l, cwh, cwl, a_all, outA);
  wc_all<<<BB*4, 256, 0, stream>>>(a_all, ctx, wch, wcl);

  gemm_split<1,0><<<(TT*BB/128)*(H/128), 256, 0, stream>>>(
      wch, wcl, h1h + BH, h1l + BH, H, woutH, woutL,
      outY, nullptr, nullptr, TT*BB, H, 2*H, H/128);
}

// Round 19
// 1420.424 us; speedup vs baseline: 2.0022x; 1.3810x over previous
//
#include <hip/hip_runtime.h>
#include <hip/hip_bf16.h>
#include <stdint.h>

// Decoder: 2-layer LSTM + Luong attention. input_feed=0 => attention deferred
// post-loop. R19 = R18 (weights in LDS, 16 waves, async gll16 h staging,
// sc0sc1 h stores, hierarchical barrier) with HI-ONLY recurrence operands:
// the K-loop reads only h0-hi / h1-hi (gate error += ~1e-4, well inside
// margin); h1 hi/lo pair still stored for the precision-critical attention
// and output-projection paths. Halves the per-phase h broadcast.

typedef __bf16 bf16_t;
typedef __bf16 bf16x8 __attribute__((ext_vector_type(8)));
typedef __bf16 bf16x4 __attribute__((ext_vector_type(4)));
typedef float f32x4 __attribute__((ext_vector_type(4)));

#define AS1 __attribute__((address_space(1)))
#define AS3 __attribute__((address_space(3)))

__device__ __forceinline__ void gll16(const bf16_t* g, bf16_t* l) {
  __builtin_amdgcn_global_load_lds((const AS1 void*)g, (AS3 void*)l, 16, 0, 0);
}

__device__ __forceinline__ float sigm(float x){ return 1.f/(1.f+expf(-x)); }

#define MFMA16(acc, a, b) acc = __builtin_amdgcn_mfma_f32_16x16x32_bf16(a, b, acc, 0,0,0)

// system write-through coherent store (proven R5/R8/R12/R14/R18)
__device__ __forceinline__ void stg_sc(bf16_t* p, bf16_t v){
  uint32_t w = (uint32_t)__builtin_bit_cast(uint16_t, v);
  asm volatile("global_store_short %0, %1, off sc0 sc1" :: "v"(p), "v"(w) : "memory");
}

// ---------------- prep kernels ----------------
__global__ void f2b(const float* __restrict__ in, bf16_t* __restrict__ outp, int n){
  int i = (blockIdx.x*256 + threadIdx.x)*4;
  if (i >= n) return;
  float4 v = *(const float4*)(in + i);
  bf16x4 o; o[0]=(bf16_t)v.x; o[1]=(bf16_t)v.y; o[2]=(bf16_t)v.z; o[3]=(bf16_t)v.w;
  *(bf16x4*)(outp + i) = o;
}

__global__ void f2b_pair(const float* __restrict__ in, bf16_t* __restrict__ oh,
                         bf16_t* __restrict__ ol, int n){
  int i = (blockIdx.x*256 + threadIdx.x)*4;
  if (i >= n) return;
  float4 v = *(const float4*)(in + i);
  float vv[4] = {v.x, v.y, v.z, v.w};
  bf16x4 h, l;
  #pragma unroll
  for (int j=0;j<4;j++){ h[j]=(bf16_t)vv[j]; l[j]=(bf16_t)(vv[j]-(float)h[j]); }
  *(bf16x4*)(oh + i) = h;
  *(bf16x4*)(ol + i) = l;
}

__global__ void bias_combine(const float* __restrict__ a, const float* __restrict__ b,
                             float* __restrict__ o, int n){
  int i = blockIdx.x*256 + threadIdx.x;
  if (i < n) o[i] = a[i] + b[i];
}

__global__ void embed_gather(const int* __restrict__ tokp, const float* __restrict__ embW,
                             bf16_t* __restrict__ xe){
  int m = blockIdx.x;
  int tokv = tokp[m];
  const float* src = embW + (size_t)tokv*1024 + threadIdx.x*4;
  float4 v = *(const float4*)src;
  bf16x4 o; o[0]=(bf16_t)v.x; o[1]=(bf16_t)v.y; o[2]=(bf16_t)v.z; o[3]=(bf16_t)v.w;
  *(bf16x4*)(xe + (size_t)m*1024 + threadIdx.x*4) = o;
}

// winT[e,d] = split(Win[d,e])
__global__ void transWin(const float* __restrict__ in, bf16_t* __restrict__ oh,
                         bf16_t* __restrict__ ol){
  __shared__ float t[32][33];
  int bi = blockIdx.x & 31, bj = blockIdx.x >> 5;
  int tx = threadIdx.x & 31, ty = threadIdx.x >> 5;  // 32 x 8
  #pragma unroll
  for (int i=0;i<4;i++){
    int d = bi*32 + ty + i*8, e = bj*32 + tx;
    t[ty+i*8][tx] = in[(size_t)d*1024 + e];
  }
  __syncthreads();
  #pragma unroll
  for (int i=0;i<4;i++){
    int e = bj*32 + ty + i*8, d = bi*32 + tx;
    float v = t[tx][ty+i*8];
    bf16_t h = (bf16_t)v;
    oh[(size_t)e*1024 + d] = h;
    ol[(size_t)e*1024 + d] = (bf16_t)(v - (float)h);
  }
}

// -------- x0g GEMM: x0gT[t][bg][g][col][16 rows] = xemb@wih0^T + bias0 --------
__global__ __launch_bounds__(256) void gemm_bt(
    const bf16_t* __restrict__ A, const bf16_t* __restrict__ Bm,
    const float* __restrict__ bias, bf16_t* __restrict__ Cout,
    int M, int N, int K, int nTN)
{
  __shared__ bf16_t sA[128*64];
  __shared__ bf16_t sB[128*64];
  int tid = threadIdx.x, lane = tid & 63, w = tid >> 6;
  int tm = blockIdx.x / nTN, tn = blockIdx.x % nTN;
  int row0 = tm*128, col0 = tn*128;
  int wr = w >> 1, wcc = w & 1;
  f32x4 acc[4][4] = {};
  for (int kt = 0; kt < K; kt += 64) {
    __syncthreads();
    #pragma unroll
    for (int i=0;i<4;i++){
      int c = i*256 + tid;
      int r = c >> 3, kk = (c & 7) << 3;
      gll16(A  + (size_t)(row0+r)*K + kt + kk, sA + (size_t)(i*256 + w*64)*8);
      gll16(Bm + (size_t)(col0+r)*K + kt + kk, sB + (size_t)(i*256 + w*64)*8);
    }
    __syncthreads();
    #pragma unroll
    for (int kk=0;kk<64;kk+=32){
      bf16x8 av[4], bv[4];
      #pragma unroll
      for (int m=0;m<4;m++) av[m] = *(const bf16x8*)(sA + (wr*64 + m*16 + (lane&15))*64 + kk + ((lane>>4)<<3));
      #pragma unroll
      for (int n=0;n<4;n++) bv[n] = *(const bf16x8*)(sB + (wcc*64 + n*16 + (lane&15))*64 + kk + ((lane>>4)<<3));
      #pragma unroll
      for (int m=0;m<4;m++)
        #pragma unroll
        for (int n=0;n<4;n++)
          acc[m][n] = __builtin_amdgcn_mfma_f32_16x16x32_bf16(av[m], bv[n], acc[m][n], 0,0,0);
    }
  }
  #pragma unroll
  for (int n=0;n<4;n++){
    int cn = col0 + wcc*64 + n*16 + (lane & 15);
    float bvv = bias[cn];
    int g = cn >> 10, col = cn & 1023;
    #pragma unroll
    for (int m=0;m<4;m++){
      int rm = row0 + wr*64 + m*16 + ((lane>>4)<<2);
      int p = rm >> 7, bgi = (rm >> 4) & 7, rr = rm & 15;
      bf16x4 o;
      #pragma unroll
      for (int r=0;r<4;r++) o[r] = (bf16_t)(acc[m][n][r] + bvv);
      *(bf16x4*)(Cout + ((((size_t)p*8+bgi)*4+g)*1024 + col)*16 + rr) = o;
    }
  }
}

// ---------------- split GEMM: hi/lo A (two K-parts) x hi/lo B, 3 combos ----------------
template<int ACT_TANH, int OUT_PAIR>
__global__ __launch_bounds__(256) void gemm_split(
    const bf16_t* __restrict__ Ah1, const bf16_t* __restrict__ Al1,
    const bf16_t* __restrict__ Ah2, const bf16_t* __restrict__ Al2, int K1,
    const bf16_t* __restrict__ Bh, const bf16_t* __restrict__ Bl,
    float* __restrict__ Cf, bf16_t* __restrict__ Ch, bf16_t* __restrict__ Cl,
    int M, int N, int K, int nTN)
{
  __shared__ bf16_t sAh[128*64], sAl[128*64], sBh[128*64], sBl[128*64];
  int tid = threadIdx.x, lane = tid & 63, w = tid >> 6;
  int tm = blockIdx.x / nTN, tn = blockIdx.x % nTN;
  int row0 = tm*128, col0 = tn*128;
  int wr = w >> 1, wcc = w & 1;
  f32x4 acc[4][4] = {};
  for (int kt = 0; kt < K; kt += 64) {
    const bf16_t *Ah, *Al; int kl;
    if (kt < K1){ Ah=Ah1; Al=Al1; kl=kt; } else { Ah=Ah2; Al=Al2; kl=kt-K1; }
    __syncthreads();
    #pragma unroll
    for (int i=0;i<4;i++){
      int c = i*256 + tid;
      int r = c >> 3, kk = (c & 7) << 3;
      gll16(Ah + (size_t)(row0+r)*K1 + kl + kk, sAh + (size_t)(i*256 + w*64)*8);
      gll16(Al + (size_t)(row0+r)*K1 + kl + kk, sAl + (size_t)(i*256 + w*64)*8);
      gll16(Bh + (size_t)(col0+r)*K + kt + kk, sBh + (size_t)(i*256 + w*64)*8);
      gll16(Bl + (size_t)(col0+r)*K + kt + kk, sBl + (size_t)(i*256 + w*64)*8);
    }
    __syncthreads();
    #pragma unroll
    for (int kk=0;kk<64;kk+=32){
      bf16x8 avh[4], avl[4], bvh[4], bvl[4];
      #pragma unroll
      for (int m=0;m<4;m++){
        int off = (wr*64 + m*16 + (lane&15))*64 + kk + ((lane>>4)<<3);
        avh[m] = *(const bf16x8*)(sAh + off);
        avl[m] = *(const bf16x8*)(sAl + off);
      }
      #pragma unroll
      for (int n=0;n<4;n++){
        int off = (wcc*64 + n*16 + (lane&15))*64 + kk + ((lane>>4)<<3);
        bvh[n] = *(const bf16x8*)(sBh + off);
        bvl[n] = *(const bf16x8*)(sBl + off);
      }
      #pragma unroll
      for (int m=0;m<4;m++)
        #pragma unroll
        for (int n=0;n<4;n++){
          acc[m][n] = __builtin_amdgcn_mfma_f32_16x16x32_bf16(avh[m], bvh[n], acc[m][n], 0,0,0);
          acc[m][n] = __builtin_amdgcn_mfma_f32_16x16x32_bf16(avl[m], bvh[n], acc[m][n], 0,0,0);
          acc[m][n] = __builtin_amdgcn_mfma_f32_16x16x32_bf16(avh[m], bvl[n], acc[m][n], 0,0,0);
        }
    }
  }
  #pragma unroll
  for (int n=0;n<4;n++){
    int cn = col0 + wcc*64 + n*16 + (lane & 15);
    #pragma unroll
    for (int m=0;m<4;m++){
      int rm = row0 + wr*64 + m*16 + ((lane>>4)<<2);
      #pragma unroll
      for (int r=0;r<4;r++){
        float v = acc[m][n][r];
        if (ACT_TANH) v = tanhf(v);
        if (OUT_PAIR){
          bf16_t h = (bf16_t)v;
          Ch[(size_t)(rm+r)*N + cn] = h;
          Cl[(size_t)(rm+r)*N + cn] = (bf16_t)(v - (float)h);
        } else {
          Cf[(size_t)(rm+r)*N + cn] = v;
        }
      }
    }
  }
}

// ---------------- persistent LSTM loop: weights in LDS, hi-only h staging ----------------
// 256 blocks x 1024 thr (16 waves = 8 row-groups rg x 2 K-halves kh).
#define NBLK 256
#define STGOFF 98304                  // 48*1024*2 bytes of weights
#define LDS_BYTES 133120              // + max(16 waves*2KB staging, sG 34816B)

__global__ __launch_bounds__(1024, 4) void lstm_loop(
    const bf16_t* __restrict__ whh0, const bf16_t* __restrict__ wih1,
    const bf16_t* __restrict__ whh1, const bf16_t* __restrict__ x0gT,
    const float* __restrict__ bias1, const float* __restrict__ c0in,
    bf16_t* __restrict__ h0h,                                // hist [65][128][1024]
    bf16_t* __restrict__ h1h, bf16_t* __restrict__ h1l,      // hist [65][128][1024]
    float* __restrict__ outH, float* __restrict__ outC, int* bar, int* done)
{
  extern __shared__ char smem[];
  bf16_t* wlds = (bf16_t*)smem;
  float*  sG   = (float*)(smem + STGOFF);    // 4 regions x [128][17] (aliases staging)

  // one-time acquire: invalidate stale L1/L2 lines (poison / prior replay)
  __threadfence();

  const int tid = threadIdx.x, lane = tid & 63, wv = tid >> 6;
  const int l15 = lane & 15, hi4 = lane >> 4;
  const int hc0 = blockIdx.x * 4;
  const int rg = wv & 7, kh = wv >> 3;

  // ---- stage weights into LDS once (XOR slot swizzle: slot ^ (row&7)) ----
  for (int e = tid; e < 6144; e += 1024){
    int m = e >> 11, r = e & 2047, n = r >> 7, kc = r & 127;
    const bf16_t* Wm = (m == 0) ? whh0 : ((m == 1) ? wih1 : whh1);
    int row = ((n >> 2) << 10) + hc0 + (n & 3);
    bf16x8 v = *(const bf16x8*)(Wm + (size_t)row*1024 + kc*8);
    *(bf16x8*)(wlds + (size_t)(m*16 + n)*1024 + (kc ^ (n & 7))*8) = v;
  }
  __syncthreads();

  // cell mapping: threads 0..511 own 1 cell per layer
  const bool cell = (tid < 512);
  const int crow = tid >> 2, q = tid & 3;
  const size_t cellix = (size_t)crow*1024 + hc0 + q;
  float c0reg = 0.f, c1reg = 0.f, bs[4] = {};
  if (cell){
    c0reg = c0in[cellix];
    c1reg = c0in[131072 + cellix];
    #pragma unroll
    for (int g=0; g<4; ++g) bs[g] = bias1[(g<<10) + hc0 + q];
  }

  // staging geometry: 2 arrays x 512 elems (2KB) per wave
  bf16_t* mybuf = (bf16_t*)(smem + STGOFF + wv*2048);
  const size_t srcoff = (size_t)(rg*16 + (lane >> 2))*1024
                      + (size_t)(((lane & 3) ^ ((lane >> 4) & 3)) * 8);
  const int rdoff = l15*32 + ((hi4 ^ ((l15 >> 2) & 3)) * 8);
  const int wbA = (0*16 + l15)*1024;
  const int wbB = (1*16 + l15)*1024;
  const int wbC = (2*16 + l15)*1024;

  for (int p = 0; p <= 64; ++p){
    const bf16_t* h0h_ = h0h + (size_t)p*131072;
    const bf16_t* h1ph = h1h + (size_t)(p >= 1 ? p-1 : 0)*131072;

    // x0g loads (dense transposed layout)
    float xg[4] = {0,0,0,0};
    if (cell && p < 64){
      int bg = crow >> 4, rr = crow & 15;
      #pragma unroll
      for (int g=0; g<4; ++g)
        xg[g] = (float)x0gT[((((size_t)p*8 + bg)*4 + g)*1024 + hc0 + q)*16 + rr];
    }

    // ---- K-loop: hi-only async-staged chunks (32 K-elems each) ----
    f32x4 accA = {}, accB = {};
    #pragma unroll
    for (int c = 0; c < 16; ++c){
      const int k0 = kh*512 + c*32;
      gll16(h0h_ + srcoff + k0, mybuf + 0*512);
      gll16(h1ph + srcoff + k0, mybuf + 1*512);
      asm volatile("s_waitcnt vmcnt(0)" ::: "memory");
      __builtin_amdgcn_sched_barrier(0);
      bf16x8 a0 = *(const bf16x8*)(mybuf + 0*512 + rdoff);
      bf16x8 a1 = *(const bf16x8*)(mybuf + 1*512 + rdoff);
      const int slot = kh*64 + c*4 + hi4;
      const int ws = (slot ^ (l15 & 7)) * 8;
      bf16x8 w0 = *(const bf16x8*)(wlds + wbA + ws);
      bf16x8 w1 = *(const bf16x8*)(wlds + wbB + ws);
      bf16x8 w2 = *(const bf16x8*)(wlds + wbC + ws);
      MFMA16(accA, a0, w0);
      MFMA16(accB, a0, w1);
      MFMA16(accB, a1, w2);
    }

    // ---- staging dead; sG (aliased) becomes live ----
    __syncthreads();
    {
      const int rowb = rg*16 + hi4*4;
      #pragma unroll
      for (int r=0;r<4;r++){
        sG[(0*2 + kh)*2176 + (rowb + r)*17 + l15] = accA[r];
        sG[(2 + kh)*2176 + (rowb + r)*17 + l15]   = accB[r];
      }
    }
    __syncthreads();

    // ---- cells ----
    if (cell){
      if (p < 64){
        float gv[4];
        #pragma unroll
        for (int g=0; g<4; ++g)
          gv[g] = sG[0*2176 + crow*17 + g*4 + q] + sG[1*2176 + crow*17 + g*4 + q] + xg[g];
        float cv = sigm(gv[1])*c0reg + sigm(gv[0])*tanhf(gv[2]);
        float hv = sigm(gv[3])*tanhf(cv);
        c0reg = cv;
        stg_sc(h0h + (size_t)(p+1)*131072 + cellix, (bf16_t)hv);
        if (p == 63){ outH[cellix] = hv; outC[cellix] = cv; }
      }
      if (p >= 1){
        float gv[4];
        #pragma unroll
        for (int g=0; g<4; ++g)
          gv[g] = sG[2*2176 + crow*17 + g*4 + q] + sG[3*2176 + crow*17 + g*4 + q] + bs[g];
        float cv = sigm(gv[1])*c1reg + sigm(gv[0])*tanhf(gv[2]);
        float hv = sigm(gv[3])*tanhf(cv);
        c1reg = cv;
        bf16_t hh = (bf16_t)hv;
        stg_sc(h1h + (size_t)p*131072 + cellix, hh);
        stg_sc(h1l + (size_t)p*131072 + cellix, (bf16_t)(hv - (float)hh));
        if (p == 64){ outH[131072 + cellix] = hv; outC[131072 + cellix] = cv; }
      }
    }

    // ---- hierarchical grid barrier: spread signal, single-flag poll ----
    if (p < 64){
      __syncthreads();   // drains each wave's vmem (incl. sc stores)
      if (tid == 0){
        __hip_atomic_fetch_add(bar + (blockIdx.x & 15)*64, 1, __ATOMIC_RELAXED, __HIP_MEMORY_SCOPE_AGENT);
        if (blockIdx.x == 0){
          const int tgt = NBLK*(p+1);
          for(;;){
            int s = 0;
            #pragma unroll
            for (int i=0;i<16;i++)
              s += __hip_atomic_load(bar + i*64, __ATOMIC_RELAXED, __HIP_MEMORY_SCOPE_AGENT);
            if (s >= tgt) break;
            __builtin_amdgcn_s_sleep(1);
          }
          __hip_atomic_store(done, p+1, __ATOMIC_RELAXED, __HIP_MEMORY_SCOPE_AGENT);
        } else {
          while (__hip_atomic_load(done, __ATOMIC_RELAXED, __HIP_MEMORY_SCOPE_AGENT) < p+1)
            __builtin_amdgcn_s_sleep(1);
        }
      }
      __syncthreads();
      asm volatile("" ::: "memory");
      __builtin_amdgcn_sched_barrier(0);
    }
  }
}

// ---------------- scores + softmax (per batch row b), post-loop ----------------
__global__ __launch_bounds__(256) void attn_sm(
    const bf16_t* __restrict__ h1h, const bf16_t* __restrict__ h1l,
    const bf16_t* __restrict__ cwh, const bf16_t* __restrict__ cwl,
    float* __restrict__ a_all, float* __restrict__ outA)
{
  __shared__ bf16_t sAh[64*64], sAl[64*64];
  __shared__ bf16_t sBh[128*64], sBl[128*64];
  __shared__ float sS[64*128];
  int b = blockIdx.x;
  int tid = threadIdx.x, lane = tid&63, w = tid>>6;
  int wr = w>>1, wcc = w&1;
  f32x4 acc[2][4] = {};
  for (int kt=0; kt<1024; kt+=64){
    __syncthreads();
    #pragma unroll
    for (int i=0;i<2;i++){
      int c = i*256+tid; int r = c>>3, kk=(c&7)<<3;
      size_t src = (size_t)(r+1)*131072 + (size_t)b*1024 + kt+kk;
      gll16(h1h + src, sAh + (size_t)(i*256 + w*64)*8);
      gll16(h1l + src, sAl + (size_t)(i*256 + w*64)*8);
    }
    #pragma unroll
    for (int i=0;i<4;i++){
      int c = i*256+tid; int br=c>>3, kk=(c&7)<<3;
      size_t src = ((size_t)b*128 + br)*1024 + kt+kk;
      gll16(cwh + src, sBh + (size_t)(i*256+w*64)*8);
      gll16(cwl + src, sBl + (size_t)(i*256+w*64)*8);
    }
    __syncthreads();
    #pragma unroll
    for (int kk=0;kk<64;kk+=32){
      bf16x8 avh[2], avl[2], bvh[4], bvl[4];
      #pragma unroll
      for (int m=0;m<2;m++){
        int off = (wr*32 + m*16 + (lane&15))*64 + kk + ((lane>>4)<<3);
        avh[m] = *(const bf16x8*)(sAh + off);
        avl[m] = *(const bf16x8*)(sAl + off);
      }
      #pragma unroll
      for (int n=0;n<4;n++){
        int off = (wcc*64 + n*16 + (lane&15))*64 + kk + ((lane>>4)<<3);
        bvh[n] = *(const bf16x8*)(sBh + off);
        bvl[n] = *(const bf16x8*)(sBl + off);
      }
      #pragma unroll
      for (int m=0;m<2;m++)
        #pragma unroll
        for (int n=0;n<4;n++){
          acc[m][n] = __builtin_amdgcn_mfma_f32_16x16x32_bf16(avh[m], bvh[n], acc[m][n], 0,0,0);
          acc[m][n] = __builtin_amdgcn_mfma_f32_16x16x32_bf16(avl[m], bvh[n], acc[m][n], 0,0,0);
          acc[m][n] = __builtin_amdgcn_mfma_f32_16x16x32_bf16(avh[m], bvl[n], acc[m][n], 0,0,0);
        }
    }
  }
  #pragma unroll
  for (int m=0;m<2;m++)
    #pragma unroll
    for (int n=0;n<4;n++)
      #pragma unroll
      for (int r=0;r<4;r++){
        int trow = wr*32 + m*16 + ((lane>>4)<<2) + r;
        int tc   = wcc*64 + n*16 + (lane&15);
        sS[trow*128+tc] = acc[m][n][r];
      }
  __syncthreads();
  for (int i=0;i<16;i++){
    int r = w*16 + i;
    float v0 = sS[r*128 + lane], v1 = sS[r*128 + 64 + lane];
    float mx = fmaxf(v0, v1);
    #pragma unroll
    for (int off=32; off; off>>=1) mx = fmaxf(mx, __shfl_xor(mx, off));
    float e0 = expf(v0-mx), e1 = expf(v1-mx);
    float sm = e0+e1;
    #pragma unroll
    for (int off=32; off; off>>=1) sm += __shfl_xor(sm, off);
    float inv = 1.f/sm;
    size_t base = ((size_t)r*128 + b)*128;
    a_all[base + lane]      = e0*inv;
    a_all[base + 64 + lane] = e1*inv;
    if (r == 63){
      outA[(size_t)b*128 + lane]      = e0*inv;
      outA[(size_t)b*128 + 64 + lane] = e1*inv;
    }
  }
}

// ---------------- wc (fp32 VALU): wc[t,b,:] = sum_s a[t,b,s]*ctx[b,s,:] ----
__global__ __launch_bounds__(256) void wc_all(
    const float* __restrict__ a_all, const float* __restrict__ ctx,
    bf16_t* __restrict__ wch, bf16_t* __restrict__ wcl)
{
  int bid = blockIdx.x;
  int b = bid & 127, tg = bid >> 7;  // tg 0..3, 16 t each
  int tid = threadIdx.x;
  __shared__ float sa[16][128];
  int t0 = tg*16;
  #pragma unroll
  for (int i=0;i<8;i++){
    int q = i*256 + tid;
    int ti = q >> 7, s = q & 127;
    sa[ti][s] = a_all[((size_t)(t0+ti)*128 + b)*128 + s];
  }
  __syncthreads();
  f32x4 acc[16];
  #pragma unroll
  for (int i=0;i<16;i++) acc[i] = f32x4{0,0,0,0};
  const float* cb = ctx + (size_t)b*128*1024 + tid*4;
  for (int s=0;s<128;s++){
    f32x4 c = *(const f32x4*)(cb + (size_t)s*1024);
    #pragma unroll
    for (int ti=0;ti<16;ti++){
      float av = sa[ti][s];
      acc[ti] += av * c;
    }
  }
  #pragma unroll
  for (int ti=0;ti<16;ti++){
    size_t m = (size_t)(t0+ti)*128 + b;
    bf16x4 h, l;
    #pragma unroll
    for (int j=0;j<4;j++){
      float v = acc[ti][j];
      h[j] = (bf16_t)v; l[j] = (bf16_t)(v - (float)h[j]);
    }
    *(bf16x4*)(wch + m*1024 + tid*4) = h;
    *(bf16x4*)(wcl + m*1024 + tid*4) = l;
  }
}

// ---------------- host ----------------
extern "C" void kernel_launch(void* const* d_in, const int* in_sizes, int n_in,
                              void* d_out, int out_size, void* d_ws, size_t ws_size,
                              hipStream_t stream)
{
  (void)in_sizes; (void)n_in; (void)out_size; (void)ws_size;
  const int TT=64, BB=128, H=1024, G=4096, BH=128*1024;

  const int*   tok  = (const int*)d_in[0];
  const float* h0   = (const float*)d_in[1];
  const float* c0   = (const float*)d_in[2];
  const float* ctx  = (const float*)d_in[3];
  const float* embW = (const float*)d_in[5];
  const float* wih  = (const float*)d_in[6];
  const float* whh  = (const float*)d_in[7];
  const float* bih  = (const float*)d_in[8];
  const float* bhh  = (const float*)d_in[9];
  const float* Win  = (const float*)d_in[10];
  const float* Wout = (const float*)d_in[11];

  float* outY = (float*)d_out;                      // [T,B,H]
  float* outH = outY + (size_t)TT*BB*H;             // [2,B,H]
  float* outC = outH + (size_t)2*BH;                // [2,B,H]
  float* outA = outC + (size_t)2*BH;                // [B,S]

  char* ws = (char*)d_ws;
  size_t o = 0;
  auto carve = [&](size_t bytes)->char* {
    char* p = ws + o; o += (bytes + 255) & ~(size_t)255; return p;
  };
  bf16_t* wihB  = (bf16_t*)carve((size_t)2*G*H*2);       // 16MB
  bf16_t* whhB  = (bf16_t*)carve((size_t)2*G*H*2);       // 16MB
  bf16_t* woutH = (bf16_t*)carve((size_t)H*2*H*2);       // 4MB
  bf16_t* woutL = (bf16_t*)carve((size_t)H*2*H*2);       // 4MB
  bf16_t* winTh = (bf16_t*)carve((size_t)H*H*2);         // 2MB
  bf16_t* winTl = (bf16_t*)carve((size_t)H*H*2);         // 2MB
  bf16_t* ctxh  = (bf16_t*)carve((size_t)BB*128*H*2);    // 32MB; loop: h0 hist; post: wch
  bf16_t* ctxl  = (bf16_t*)carve((size_t)BB*128*H*2);    // 32MB; post: wcl
  bf16_t* cwh   = (bf16_t*)carve((size_t)BB*128*H*2);    // 32MB (pre: xemb overlays)
  bf16_t* cwl   = (bf16_t*)carve((size_t)BB*128*H*2);    // 32MB
  bf16_t* x0gT  = (bf16_t*)carve((size_t)TT*BB*G*2);     // 64MB
  bf16_t* h1h   = (bf16_t*)carve((size_t)(TT+1)*BH*2);   // 17MB history
  bf16_t* h1l   = (bf16_t*)carve((size_t)(TT+1)*BH*2);   // 17MB
  float*  a_all = (float*)carve((size_t)TT*BB*128*4);    // 4MB
  float*  biasF = (float*)carve((size_t)2*G*4);
  int*    bar   = (int*)carve(16*64*4);
  int*    done  = (int*)carve(256);

  bf16_t* xemb   = cwh;          // overlays ctxW-hi (dead until ctxW GEMM)
  bf16_t* h0hist = ctxh;         // h0 history [65][128][1024] (ctx dead after ctxW GEMM)
  bf16_t* wch    = ctxh;         // post-loop overlay (h0 hist dead then)
  bf16_t* wcl    = ctxl;

  // ---- prep ----
  hipMemsetAsync(bar, 0, 16*64*4, stream);
  hipMemsetAsync(done, 0, 256, stream);
  f2b<<<(2*G*H)/1024, 256, 0, stream>>>(wih, wihB, 2*G*H);
  f2b<<<(2*G*H)/1024, 256, 0, stream>>>(whh, whhB, 2*G*H);
  f2b_pair<<<(H*2*H)/1024, 256, 0, stream>>>(Wout, woutH, woutL, H*2*H);
  f2b_pair<<<(BB*128*H)/1024, 256, 0, stream>>>(ctx, ctxh, ctxl, BB*128*H);
  f2b_pair<<<BH/1024, 256, 0, stream>>>(h0 + BH, h1h, h1l, BH);
  transWin<<<1024, 256, 0, stream>>>(Win, winTh, winTl);
  bias_combine<<<(2*G)/256, 256, 0, stream>>>(bih, bhh, biasF, 2*G);
  embed_gather<<<TT*BB, 256, 0, stream>>>(tok, embW, xemb);

  // ---- one-time GEMMs ----
  gemm_bt<<<(TT*BB/128)*(G/128), 256, 0, stream>>>(xemb, wihB, biasF, x0gT, TT*BB, G, H, G/128);
  gemm_split<0,1><<<(BB*128/128)*(H/128), 256, 0, stream>>>(
      ctxh, ctxl, ctxh, ctxl, H, winTh, winTl,
      nullptr, cwh, cwl, BB*128, H, H, H/128);

  // h0 layer-0 initial state (hi only) -> h0 history slot 0 (ctx region now dead)
  f2b<<<BH/1024, 256, 0, stream>>>(h0, h0hist, BH);

  // ---- persistent recurrence ----
  hipFuncSetAttribute((const void*)lstm_loop,
                      hipFuncAttributeMaxDynamicSharedMemorySize, LDS_BYTES);
  lstm_loop<<<NBLK, 1024, LDS_BYTES, stream>>>(
      whhB, wihB + (size_t)G*H, whhB + (size_t)G*H, x0gT, biasF + G, c0,
      h0hist, h1h, h1l, outH, outC, bar, done);

  // ---- post-loop attention ----
  attn_sm<<<BB, 256, 0, stream>>>(h1h, h1l, cwh, cwl, a_all, outA);
  wc_all<<<BB*4, 256, 0, stream>>>(a_all, ctx, wch, wcl);

  gemm_split<1,0><<<(TT*BB/128)*(H/128), 256, 0, stream>>>(
      wch, wcl, h1h + BH, h1l + BH, H, woutH, woutL,
      outY, nullptr, nullptr, TT*BB, H, 2*H, H/128);
}

// Round 20
// 1362.145 us; speedup vs baseline: 2.0879x; 1.0428x over previous
//
#include <hip/hip_runtime.h>
#include <hip/hip_bf16.h>
#include <stdint.h>

// Decoder: 2-layer LSTM + Luong attention. input_feed=0 => attention deferred
// post-loop. R20 = R19 (weights in LDS, 16 waves, hi-only h recurrence,
// sc0sc1 h stores, hierarchical barrier) + depth-1 counted-vmcnt double-
// buffered staging: issue batch c+1, vmcnt(2) waits batch c only, lgkmcnt(0)
// guards buffer reuse. Overlaps chunk drains with compute+issue.

typedef __bf16 bf16_t;
typedef __bf16 bf16x8 __attribute__((ext_vector_type(8)));
typedef __bf16 bf16x4 __attribute__((ext_vector_type(4)));
typedef float f32x4 __attribute__((ext_vector_type(4)));

#define AS1 __attribute__((address_space(1)))
#define AS3 __attribute__((address_space(3)))

__device__ __forceinline__ void gll16(const bf16_t* g, bf16_t* l) {
  __builtin_amdgcn_global_load_lds((const AS1 void*)g, (AS3 void*)l, 16, 0, 0);
}

__device__ __forceinline__ float sigm(float x){ return 1.f/(1.f+expf(-x)); }

#define MFMA16(acc, a, b) acc = __builtin_amdgcn_mfma_f32_16x16x32_bf16(a, b, acc, 0,0,0)

// system write-through coherent store (proven R5..R19)
__device__ __forceinline__ void stg_sc(bf16_t* p, bf16_t v){
  uint32_t w = (uint32_t)__builtin_bit_cast(uint16_t, v);
  asm volatile("global_store_short %0, %1, off sc0 sc1" :: "v"(p), "v"(w) : "memory");
}

// ---------------- prep kernels ----------------
__global__ void f2b(const float* __restrict__ in, bf16_t* __restrict__ outp, int n){
  int i = (blockIdx.x*256 + threadIdx.x)*4;
  if (i >= n) return;
  float4 v = *(const float4*)(in + i);
  bf16x4 o; o[0]=(bf16_t)v.x; o[1]=(bf16_t)v.y; o[2]=(bf16_t)v.z; o[3]=(bf16_t)v.w;
  *(bf16x4*)(outp + i) = o;
}

__global__ void f2b_pair(const float* __restrict__ in, bf16_t* __restrict__ oh,
                         bf16_t* __restrict__ ol, int n){
  int i = (blockIdx.x*256 + threadIdx.x)*4;
  if (i >= n) return;
  float4 v = *(const float4*)(in + i);
  float vv[4] = {v.x, v.y, v.z, v.w};
  bf16x4 h, l;
  #pragma unroll
  for (int j=0;j<4;j++){ h[j]=(bf16_t)vv[j]; l[j]=(bf16_t)(vv[j]-(float)h[j]); }
  *(bf16x4*)(oh + i) = h;
  *(bf16x4*)(ol + i) = l;
}

__global__ void bias_combine(const float* __restrict__ a, const float* __restrict__ b,
                             float* __restrict__ o, int n){
  int i = blockIdx.x*256 + threadIdx.x;
  if (i < n) o[i] = a[i] + b[i];
}

__global__ void embed_gather(const int* __restrict__ tokp, const float* __restrict__ embW,
                             bf16_t* __restrict__ xe){
  int m = blockIdx.x;
  int tokv = tokp[m];
  const float* src = embW + (size_t)tokv*1024 + threadIdx.x*4;
  float4 v = *(const float4*)src;
  bf16x4 o; o[0]=(bf16_t)v.x; o[1]=(bf16_t)v.y; o[2]=(bf16_t)v.z; o[3]=(bf16_t)v.w;
  *(bf16x4*)(xe + (size_t)m*1024 + threadIdx.x*4) = o;
}

// winT[e,d] = split(Win[d,e])
__global__ void transWin(const float* __restrict__ in, bf16_t* __restrict__ oh,
                         bf16_t* __restrict__ ol){
  __shared__ float t[32][33];
  int bi = blockIdx.x & 31, bj = blockIdx.x >> 5;
  int tx = threadIdx.x & 31, ty = threadIdx.x >> 5;  // 32 x 8
  #pragma unroll
  for (int i=0;i<4;i++){
    int d = bi*32 + ty + i*8, e = bj*32 + tx;
    t[ty+i*8][tx] = in[(size_t)d*1024 + e];
  }
  __syncthreads();
  #pragma unroll
  for (int i=0;i<4;i++){
    int e = bj*32 + ty + i*8, d = bi*32 + tx;
    float v = t[tx][ty+i*8];
    bf16_t h = (bf16_t)v;
    oh[(size_t)e*1024 + d] = h;
    ol[(size_t)e*1024 + d] = (bf16_t)(v - (float)h);
  }
}

// -------- x0g GEMM: x0gT[t][bg][g][col][16 rows] = xemb@wih0^T + bias0 --------
__global__ __launch_bounds__(256) void gemm_bt(
    const bf16_t* __restrict__ A, const bf16_t* __restrict__ Bm,
    const float* __restrict__ bias, bf16_t* __restrict__ Cout,
    int M, int N, int K, int nTN)
{
  __shared__ bf16_t sA[128*64];
  __shared__ bf16_t sB[128*64];
  int tid = threadIdx.x, lane = tid & 63, w = tid >> 6;
  int tm = blockIdx.x / nTN, tn = blockIdx.x % nTN;
  int row0 = tm*128, col0 = tn*128;
  int wr = w >> 1, wcc = w & 1;
  f32x4 acc[4][4] = {};
  for (int kt = 0; kt < K; kt += 64) {
    __syncthreads();
    #pragma unroll
    for (int i=0;i<4;i++){
      int c = i*256 + tid;
      int r = c >> 3, kk = (c & 7) << 3;
      gll16(A  + (size_t)(row0+r)*K + kt + kk, sA + (size_t)(i*256 + w*64)*8);
      gll16(Bm + (size_t)(col0+r)*K + kt + kk, sB + (size_t)(i*256 + w*64)*8);
    }
    __syncthreads();
    #pragma unroll
    for (int kk=0;kk<64;kk+=32){
      bf16x8 av[4], bv[4];
      #pragma unroll
      for (int m=0;m<4;m++) av[m] = *(const bf16x8*)(sA + (wr*64 + m*16 + (lane&15))*64 + kk + ((lane>>4)<<3));
      #pragma unroll
      for (int n=0;n<4;n++) bv[n] = *(const bf16x8*)(sB + (wcc*64 + n*16 + (lane&15))*64 + kk + ((lane>>4)<<3));
      #pragma unroll
      for (int m=0;m<4;m++)
        #pragma unroll
        for (int n=0;n<4;n++)
          acc[m][n] = __builtin_amdgcn_mfma_f32_16x16x32_bf16(av[m], bv[n], acc[m][n], 0,0,0);
    }
  }
  #pragma unroll
  for (int n=0;n<4;n++){
    int cn = col0 + wcc*64 + n*16 + (lane & 15);
    float bvv = bias[cn];
    int g = cn >> 10, col = cn & 1023;
    #pragma unroll
    for (int m=0;m<4;m++){
      int rm = row0 + wr*64 + m*16 + ((lane>>4)<<2);
      int p = rm >> 7, bgi = (rm >> 4) & 7, rr = rm & 15;
      bf16x4 o;
      #pragma unroll
      for (int r=0;r<4;r++) o[r] = (bf16_t)(acc[m][n][r] + bvv);
      *(bf16x4*)(Cout + ((((size_t)p*8+bgi)*4+g)*1024 + col)*16 + rr) = o;
    }
  }
}

// ---------------- split GEMM: hi/lo A (two K-parts) x hi/lo B, 3 combos ----------------
template<int ACT_TANH, int OUT_PAIR>
__global__ __launch_bounds__(256) void gemm_split(
    const bf16_t* __restrict__ Ah1, const bf16_t* __restrict__ Al1,
    const bf16_t* __restrict__ Ah2, const bf16_t* __restrict__ Al2, int K1,
    const bf16_t* __restrict__ Bh, const bf16_t* __restrict__ Bl,
    float* __restrict__ Cf, bf16_t* __restrict__ Ch, bf16_t* __restrict__ Cl,
    int M, int N, int K, int nTN)
{
  __shared__ bf16_t sAh[128*64], sAl[128*64], sBh[128*64], sBl[128*64];
  int tid = threadIdx.x, lane = tid & 63, w = tid >> 6;
  int tm = blockIdx.x / nTN, tn = blockIdx.x % nTN;
  int row0 = tm*128, col0 = tn*128;
  int wr = w >> 1, wcc = w & 1;
  f32x4 acc[4][4] = {};
  for (int kt = 0; kt < K; kt += 64) {
    const bf16_t *Ah, *Al; int kl;
    if (kt < K1){ Ah=Ah1; Al=Al1; kl=kt; } else { Ah=Ah2; Al=Al2; kl=kt-K1; }
    __syncthreads();
    #pragma unroll
    for (int i=0;i<4;i++){
      int c = i*256 + tid;
      int r = c >> 3, kk = (c & 7) << 3;
      gll16(Ah + (size_t)(row0+r)*K1 + kl + kk, sAh + (size_t)(i*256 + w*64)*8);
      gll16(Al + (size_t)(row0+r)*K1 + kl + kk, sAl + (size_t)(i*256 + w*64)*8);
      gll16(Bh + (size_t)(col0+r)*K + kt + kk, sBh + (size_t)(i*256 + w*64)*8);
      gll16(Bl + (size_t)(col0+r)*K + kt + kk, sBl + (size_t)(i*256 + w*64)*8);
    }
    __syncthreads();
    #pragma unroll
    for (int kk=0;kk<64;kk+=32){
      bf16x8 avh[4], avl[4], bvh[4], bvl[4];
      #pragma unroll
      for (int m=0;m<4;m++){
        int off = (wr*64 + m*16 + (lane&15))*64 + kk + ((lane>>4)<<3);
        avh[m] = *(const bf16x8*)(sAh + off);
        avl[m] = *(const bf16x8*)(sAl + off);
      }
      #pragma unroll
      for (int n=0;n<4;n++){
        int off = (wcc*64 + n*16 + (lane&15))*64 + kk + ((lane>>4)<<3);
        bvh[n] = *(const bf16x8*)(sBh + off);
        bvl[n] = *(const bf16x8*)(sBl + off);
      }
      #pragma unroll
      for (int m=0;m<4;m++)
        #pragma unroll
        for (int n=0;n<4;n++){
          acc[m][n] = __builtin_amdgcn_mfma_f32_16x16x32_bf16(avh[m], bvh[n], acc[m][n], 0,0,0);
          acc[m][n] = __builtin_amdgcn_mfma_f32_16x16x32_bf16(avl[m], bvh[n], acc[m][n], 0,0,0);
          acc[m][n] = __builtin_amdgcn_mfma_f32_16x16x32_bf16(avh[m], bvl[n], acc[m][n], 0,0,0);
        }
    }
  }
  #pragma unroll
  for (int n=0;n<4;n++){
    int cn = col0 + wcc*64 + n*16 + (lane & 15);
    #pragma unroll
    for (int m=0;m<4;m++){
      int rm = row0 + wr*64 + m*16 + ((lane>>4)<<2);
      #pragma unroll
      for (int r=0;r<4;r++){
        float v = acc[m][n][r];
        if (ACT_TANH) v = tanhf(v);
        if (OUT_PAIR){
          bf16_t h = (bf16_t)v;
          Ch[(size_t)(rm+r)*N + cn] = h;
          Cl[(size_t)(rm+r)*N + cn] = (bf16_t)(v - (float)h);
        } else {
          Cf[(size_t)(rm+r)*N + cn] = v;
        }
      }
    }
  }
}

// ---------------- persistent LSTM loop: hi-only, counted double-buffer ----------------
// 256 blocks x 1024 thr (16 waves = 8 row-groups rg x 2 K-halves kh).
#define NBLK 256
#define STGOFF 98304                  // 48*1024*2 bytes of weights
#define LDS_BYTES 163840              // + 16 waves * 2 x 2KB staging (sG aliased)

__global__ __launch_bounds__(1024, 4) void lstm_loop(
    const bf16_t* __restrict__ whh0, const bf16_t* __restrict__ wih1,
    const bf16_t* __restrict__ whh1, const bf16_t* __restrict__ x0gT,
    const float* __restrict__ bias1, const float* __restrict__ c0in,
    bf16_t* __restrict__ h0h,                                // hist [65][128][1024]
    bf16_t* __restrict__ h1h, bf16_t* __restrict__ h1l,      // hist [65][128][1024]
    float* __restrict__ outH, float* __restrict__ outC, int* bar, int* done)
{
  extern __shared__ char smem[];
  bf16_t* wlds = (bf16_t*)smem;
  float*  sG   = (float*)(smem + STGOFF);    // 4 regions x [128][17] (aliases staging)

  // one-time acquire: invalidate stale L1/L2 lines (poison / prior replay)
  __threadfence();

  const int tid = threadIdx.x, lane = tid & 63, wv = tid >> 6;
  const int l15 = lane & 15, hi4 = lane >> 4;
  const int hc0 = blockIdx.x * 4;
  const int rg = wv & 7, kh = wv >> 3;

  // ---- stage weights into LDS once (XOR slot swizzle: slot ^ (row&7)) ----
  for (int e = tid; e < 6144; e += 1024){
    int m = e >> 11, r = e & 2047, n = r >> 7, kc = r & 127;
    const bf16_t* Wm = (m == 0) ? whh0 : ((m == 1) ? wih1 : whh1);
    int row = ((n >> 2) << 10) + hc0 + (n & 3);
    bf16x8 v = *(const bf16x8*)(Wm + (size_t)row*1024 + kc*8);
    *(bf16x8*)(wlds + (size_t)(m*16 + n)*1024 + (kc ^ (n & 7))*8) = v;
  }
  __syncthreads();

  // cell mapping: threads 0..511 own 1 cell per layer
  const bool cell = (tid < 512);
  const int crow = tid >> 2, q = tid & 3;
  const size_t cellix = (size_t)crow*1024 + hc0 + q;
  float c0reg = 0.f, c1reg = 0.f, bs[4] = {};
  if (cell){
    c0reg = c0in[cellix];
    c1reg = c0in[131072 + cellix];
    #pragma unroll
    for (int g=0; g<4; ++g) bs[g] = bias1[(g<<10) + hc0 + q];
  }

  // staging: 2 rotating buffers of 2KB (2 arrays x 512 elems) per wave
  bf16_t* mybuf = (bf16_t*)(smem + STGOFF + wv*4096);
  const size_t srcoff = (size_t)(rg*16 + (lane >> 2))*1024
                      + (size_t)(((lane & 3) ^ ((lane >> 4) & 3)) * 8);
  const int rdoff = l15*32 + ((hi4 ^ ((l15 >> 2) & 3)) * 8);
  const int wbA = (0*16 + l15)*1024;
  const int wbB = (1*16 + l15)*1024;
  const int wbC = (2*16 + l15)*1024;

  for (int p = 0; p <= 64; ++p){
    const bf16_t* h0h_ = h0h + (size_t)p*131072;
    const bf16_t* h1ph = h1h + (size_t)(p >= 1 ? p-1 : 0)*131072;

    // x0g loads (dense transposed layout); drained by first counted wait
    float xg[4] = {0,0,0,0};
    if (cell && p < 64){
      int bg = crow >> 4, rr = crow & 15;
      #pragma unroll
      for (int g=0; g<4; ++g)
        xg[g] = (float)x0gT[((((size_t)p*8 + bg)*4 + g)*1024 + hc0 + q)*16 + rr];
    }

    // ---- K-loop: depth-1 counted-vmcnt double-buffered pipeline ----
    f32x4 accA = {}, accB = {};
    {
      // prologue: batch 0 into buffer 0
      gll16(h0h_ + srcoff + kh*512, mybuf + 0);
      gll16(h1ph + srcoff + kh*512, mybuf + 512);
      #pragma unroll
      for (int c = 0; c < 16; ++c){
        const int cur = (c & 1) * 1024;
        if (c < 15){
          const int alt = ((c+1) & 1) * 1024;
          const int k1 = kh*512 + (c+1)*32;
          gll16(h0h_ + srcoff + k1, mybuf + alt);
          gll16(h1ph + srcoff + k1, mybuf + alt + 512);
          asm volatile("s_waitcnt vmcnt(2)" ::: "memory");  // batch c landed
        } else {
          asm volatile("s_waitcnt vmcnt(0)" ::: "memory");
        }
        __builtin_amdgcn_sched_barrier(0);
        bf16x8 a0 = *(const bf16x8*)(mybuf + cur + rdoff);
        bf16x8 a1 = *(const bf16x8*)(mybuf + cur + 512 + rdoff);
        asm volatile("s_waitcnt lgkmcnt(0)" ::: "memory");  // frags in VGPR; buffer reusable
        __builtin_amdgcn_sched_barrier(0);
        const int slot = kh*64 + c*4 + hi4;
        const int ws = (slot ^ (l15 & 7)) * 8;
        bf16x8 w0 = *(const bf16x8*)(wlds + wbA + ws);
        bf16x8 w1 = *(const bf16x8*)(wlds + wbB + ws);
        bf16x8 w2 = *(const bf16x8*)(wlds + wbC + ws);
        MFMA16(accA, a0, w0);
        MFMA16(accB, a0, w1);
        MFMA16(accB, a1, w2);
      }
    }

    // ---- staging dead; sG (aliased) becomes live ----
    __syncthreads();
    {
      const int rowb = rg*16 + hi4*4;
      #pragma unroll
      for (int r=0;r<4;r++){
        sG[(0*2 + kh)*2176 + (rowb + r)*17 + l15] = accA[r];
        sG[(2 + kh)*2176 + (rowb + r)*17 + l15]   = accB[r];
      }
    }
    __syncthreads();

    // ---- cells ----
    if (cell){
      if (p < 64){
        float gv[4];
        #pragma unroll
        for (int g=0; g<4; ++g)
          gv[g] = sG[0*2176 + crow*17 + g*4 + q] + sG[1*2176 + crow*17 + g*4 + q] + xg[g];
        float cv = sigm(gv[1])*c0reg + sigm(gv[0])*tanhf(gv[2]);
        float hv = sigm(gv[3])*tanhf(cv);
        c0reg = cv;
        stg_sc(h0h + (size_t)(p+1)*131072 + cellix, (bf16_t)hv);
        if (p == 63){ outH[cellix] = hv; outC[cellix] = cv; }
      }
      if (p >= 1){
        float gv[4];
        #pragma unroll
        for (int g=0; g<4; ++g)
          gv[g] = sG[2*2176 + crow*17 + g*4 + q] + sG[3*2176 + crow*17 + g*4 + q] + bs[g];
        float cv = sigm(gv[1])*c1reg + sigm(gv[0])*tanhf(gv[2]);
        float hv = sigm(gv[3])*tanhf(cv);
        c1reg = cv;
        bf16_t hh = (bf16_t)hv;
        stg_sc(h1h + (size_t)p*131072 + cellix, hh);
        stg_sc(h1l + (size_t)p*131072 + cellix, (bf16_t)(hv - (float)hh));
        if (p == 64){ outH[131072 + cellix] = hv; outC[131072 + cellix] = cv; }
      }
    }

    // ---- hierarchical grid barrier: spread signal, single-flag poll ----
    if (p < 64){
      __syncthreads();   // drains each wave's vmem (incl. sc stores)
      if (tid == 0){
        __hip_atomic_fetch_add(bar + (blockIdx.x & 15)*64, 1, __ATOMIC_RELAXED, __HIP_MEMORY_SCOPE_AGENT);
        if (blockIdx.x == 0){
          const int tgt = NBLK*(p+1);
          for(;;){
            int s = 0;
            #pragma unroll
            for (int i=0;i<16;i++)
              s += __hip_atomic_load(bar + i*64, __ATOMIC_RELAXED, __HIP_MEMORY_SCOPE_AGENT);
            if (s >= tgt) break;
            __builtin_amdgcn_s_sleep(1);
          }
          __hip_atomic_store(done, p+1, __ATOMIC_RELAXED, __HIP_MEMORY_SCOPE_AGENT);
        } else {
          while (__hip_atomic_load(done, __ATOMIC_RELAXED, __HIP_MEMORY_SCOPE_AGENT) < p+1)
            __builtin_amdgcn_s_sleep(1);
        }
      }
      __syncthreads();
      asm volatile("" ::: "memory");
      __builtin_amdgcn_sched_barrier(0);
    }
  }
}

// ---------------- scores + softmax (per batch row b), post-loop ----------------
__global__ __launch_bounds__(256) void attn_sm(
    const bf16_t* __restrict__ h1h, const bf16_t* __restrict__ h1l,
    const bf16_t* __restrict__ cwh, const bf16_t* __restrict__ cwl,
    float* __restrict__ a_all, float* __restrict__ outA)
{
  __shared__ bf16_t sAh[64*64], sAl[64*64];
  __shared__ bf16_t sBh[128*64], sBl[128*64];
  __shared__ float sS[64*128];
  int b = blockIdx.x;
  int tid = threadIdx.x, lane = tid&63, w = tid>>6;
  int wr = w>>1, wcc = w&1;
  f32x4 acc[2][4] = {};
  for (int kt=0; kt<1024; kt+=64){
    __syncthreads();
    #pragma unroll
    for (int i=0;i<2;i++){
      int c = i*256+tid; int r = c>>3, kk=(c&7)<<3;
      size_t src = (size_t)(r+1)*131072 + (size_t)b*1024 + kt+kk;
      gll16(h1h + src, sAh + (size_t)(i*256 + w*64)*8);
      gll16(h1l + src, sAl + (size_t)(i*256 + w*64)*8);
    }
    #pragma unroll
    for (int i=0;i<4;i++){
      int c = i*256+tid; int br=c>>3, kk=(c&7)<<3;
      size_t src = ((size_t)b*128 + br)*1024 + kt+kk;
      gll16(cwh + src, sBh + (size_t)(i*256+w*64)*8);
      gll16(cwl + src, sBl + (size_t)(i*256+w*64)*8);
    }
    __syncthreads();
    #pragma unroll
    for (int kk=0;kk<64;kk+=32){
      bf16x8 avh[2], avl[2], bvh[4], bvl[4];
      #pragma unroll
      for (int m=0;m<2;m++){
        int off = (wr*32 + m*16 + (lane&15))*64 + kk + ((lane>>4)<<3);
        avh[m] = *(const bf16x8*)(sAh + off);
        avl[m] = *(const bf16x8*)(sAl + off);
      }
      #pragma unroll
      for (int n=0;n<4;n++){
        int off = (wcc*64 + n*16 + (lane&15))*64 + kk + ((lane>>4)<<3);
        bvh[n] = *(const bf16x8*)(sBh + off);
        bvl[n] = *(const bf16x8*)(sBl + off);
      }
      #pragma unroll
      for (int m=0;m<2;m++)
        #pragma unroll
        for (int n=0;n<4;n++){
          acc[m][n] = __builtin_amdgcn_mfma_f32_16x16x32_bf16(avh[m], bvh[n], acc[m][n], 0,0,0);
          acc[m][n] = __builtin_amdgcn_mfma_f32_16x16x32_bf16(avl[m], bvh[n], acc[m][n], 0,0,0);
          acc[m][n] = __builtin_amdgcn_mfma_f32_16x16x32_bf16(avh[m], bvl[n], acc[m][n], 0,0,0);
        }
    }
  }
  #pragma unroll
  for (int m=0;m<2;m++)
    #pragma unroll
    for (int n=0;n<4;n++)
      #pragma unroll
      for (int r=0;r<4;r++){
        int trow = wr*32 + m*16 + ((lane>>4)<<2) + r;
        int tc   = wcc*64 + n*16 + (lane&15);
        sS[trow*128+tc] = acc[m][n][r];
      }
  __syncthreads();
  for (int i=0;i<16;i++){
    int r = w*16 + i;
    float v0 = sS[r*128 + lane], v1 = sS[r*128 + 64 + lane];
    float mx = fmaxf(v0, v1);
    #pragma unroll
    for (int off=32; off; off>>=1) mx = fmaxf(mx, __shfl_xor(mx, off));
    float e0 = expf(v0-mx), e1 = expf(v1-mx);
    float sm = e0+e1;
    #pragma unroll
    for (int off=32; off; off>>=1) sm += __shfl_xor(sm, off);
    float inv = 1.f/sm;
    size_t base = ((size_t)r*128 + b)*128;
    a_all[base + lane]      = e0*inv;
    a_all[base + 64 + lane] = e1*inv;
    if (r == 63){
      outA[(size_t)b*128 + lane]      = e0*inv;
      outA[(size_t)b*128 + 64 + lane] = e1*inv;
    }
  }
}

// ---------------- wc (fp32 VALU): wc[t,b,:] = sum_s a[t,b,s]*ctx[b,s,:] ----
__global__ __launch_bounds__(256) void wc_all(
    const float* __restrict__ a_all, const float* __restrict__ ctx,
    bf16_t* __restrict__ wch, bf16_t* __restrict__ wcl)
{
  int bid = blockIdx.x;
  int b = bid & 127, tg = bid >> 7;  // tg 0..3, 16 t each
  int tid = threadIdx.x;
  __shared__ float sa[16][128];
  int t0 = tg*16;
  #pragma unroll
  for (int i=0;i<8;i++){
    int q = i*256 + tid;
    int ti = q >> 7, s = q & 127;
    sa[ti][s] = a_all[((size_t)(t0+ti)*128 + b)*128 + s];
  }
  __syncthreads();
  f32x4 acc[16];
  #pragma unroll
  for (int i=0;i<16;i++) acc[i] = f32x4{0,0,0,0};
  const float* cb = ctx + (size_t)b*128*1024 + tid*4;
  for (int s=0;s<128;s++){
    f32x4 c = *(const f32x4*)(cb + (size_t)s*1024);
    #pragma unroll
    for (int ti=0;ti<16;ti++){
      float av = sa[ti][s];
      acc[ti] += av * c;
    }
  }
  #pragma unroll
  for (int ti=0;ti<16;ti++){
    size_t m = (size_t)(t0+ti)*128 + b;
    bf16x4 h, l;
    #pragma unroll
    for (int j=0;j<4;j++){
      float v = acc[ti][j];
      h[j] = (bf16_t)v; l[j] = (bf16_t)(v - (float)h[j]);
    }
    *(bf16x4*)(wch + m*1024 + tid*4) = h;
    *(bf16x4*)(wcl + m*1024 + tid*4) = l;
  }
}

// ---------------- host ----------------
extern "C" void kernel_launch(void* const* d_in, const int* in_sizes, int n_in,
                              void* d_out, int out_size, void* d_ws, size_t ws_size,
                              hipStream_t stream)
{
  (void)in_sizes; (void)n_in; (void)out_size; (void)ws_size;
  const int TT=64, BB=128, H=1024, G=4096, BH=128*1024;

  const int*   tok  = (const int*)d_in[0];
  const float* h0   = (const float*)d_in[1];
  const float* c0   = (const float*)d_in[2];
  const float* ctx  = (const float*)d_in[3];
  const float* embW = (const float*)d_in[5];
  const float* wih  = (const float*)d_in[6];
  const float* whh  = (const float*)d_in[7];
  const float* bih  = (const float*)d_in[8];
  const float* bhh  = (const float*)d_in[9];
  const float* Win  = (const float*)d_in[10];
  const float* Wout = (const float*)d_in[11];

  float* outY = (float*)d_out;                      // [T,B,H]
  float* outH = outY + (size_t)TT*BB*H;             // [2,B,H]
  float* outC = outH + (size_t)2*BH;                // [2,B,H]
  float* outA = outC + (size_t)2*BH;                // [B,S]

  char* ws = (char*)d_ws;
  size_t o = 0;
  auto carve = [&](size_t bytes)->char* {
    char* p = ws + o; o += (bytes + 255) & ~(size_t)255; return p;
  };
  bf16_t* wihB  = (bf16_t*)carve((size_t)2*G*H*2);       // 16MB
  bf16_t* whhB  = (bf16_t*)carve((size_t)2*G*H*2);       // 16MB
  bf16_t* woutH = (bf16_t*)carve((size_t)H*2*H*2);       // 4MB
  bf16_t* woutL = (bf16_t*)carve((size_t)H*2*H*2);       // 4MB
  bf16_t* winTh = (bf16_t*)carve((size_t)H*H*2);         // 2MB
  bf16_t* winTl = (bf16_t*)carve((size_t)H*H*2);         // 2MB
  bf16_t* ctxh  = (bf16_t*)carve((size_t)BB*128*H*2);    // 32MB; loop: h0 hist; post: wch
  bf16_t* ctxl  = (bf16_t*)carve((size_t)BB*128*H*2);    // 32MB; post: wcl
  bf16_t* cwh   = (bf16_t*)carve((size_t)BB*128*H*2);    // 32MB (pre: xemb overlays)
  bf16_t* cwl   = (bf16_t*)carve((size_t)BB*128*H*2);    // 32MB
  bf16_t* x0gT  = (bf16_t*)carve((size_t)TT*BB*G*2);     // 64MB
  bf16_t* h1h   = (bf16_t*)carve((size_t)(TT+1)*BH*2);   // 17MB history
  bf16_t* h1l   = (bf16_t*)carve((size_t)(TT+1)*BH*2);   // 17MB
  float*  a_all = (float*)carve((size_t)TT*BB*128*4);    // 4MB
  float*  biasF = (float*)carve((size_t)2*G*4);
  int*    bar   = (int*)carve(16*64*4);
  int*    done  = (int*)carve(256);

  bf16_t* xemb   = cwh;          // overlays ctxW-hi (dead until ctxW GEMM)
  bf16_t* h0hist = ctxh;         // h0 history [65][128][1024] (ctx dead after ctxW GEMM)
  bf16_t* wch    = ctxh;         // post-loop overlay (h0 hist dead then)
  bf16_t* wcl    = ctxl;

  // ---- prep ----
  hipMemsetAsync(bar, 0, 16*64*4, stream);
  hipMemsetAsync(done, 0, 256, stream);
  f2b<<<(2*G*H)/1024, 256, 0, stream>>>(wih, wihB, 2*G*H);
  f2b<<<(2*G*H)/1024, 256, 0, stream>>>(whh, whhB, 2*G*H);
  f2b_pair<<<(H*2*H)/1024, 256, 0, stream>>>(Wout, woutH, woutL, H*2*H);
  f2b_pair<<<(BB*128*H)/1024, 256, 0, stream>>>(ctx, ctxh, ctxl, BB*128*H);
  f2b_pair<<<BH/1024, 256, 0, stream>>>(h0 + BH, h1h, h1l, BH);
  transWin<<<1024, 256, 0, stream>>>(Win, winTh, winTl);
  bias_combine<<<(2*G)/256, 256, 0, stream>>>(bih, bhh, biasF, 2*G);
  embed_gather<<<TT*BB, 256, 0, stream>>>(tok, embW, xemb);

  // ---- one-time GEMMs ----
  gemm_bt<<<(TT*BB/128)*(G/128), 256, 0, stream>>>(xemb, wihB, biasF, x0gT, TT*BB, G, H, G/128);
  gemm_split<0,1><<<(BB*128/128)*(H/128), 256, 0, stream>>>(
      ctxh, ctxl, ctxh, ctxl, H, winTh, winTl,
      nullptr, cwh, cwl, BB*128, H, H, H/128);

  // h0 layer-0 initial state (hi only) -> h0 history slot 0 (ctx region now dead)
  f2b<<<BH/1024, 256, 0, stream>>>(h0, h0hist, BH);

  // ---- persistent recurrence ----
  hipFuncSetAttribute((const void*)lstm_loop,
                      hipFuncAttributeMaxDynamicSharedMemorySize, LDS_BYTES);
  lstm_loop<<<NBLK, 1024, LDS_BYTES, stream>>>(
      whhB, wihB + (size_t)G*H, whhB + (size_t)G*H, x0gT, biasF + G, c0,
      h0hist, h1h, h1l, outH, outC, bar, done);

  // ---- post-loop attention ----
  attn_sm<<<BB, 256, 0, stream>>>(h1h, h1l, cwh, cwl, a_all, outA);
  wc_all<<<BB*4, 256, 0, stream>>>(a_all, ctx, wch, wcl);

  gemm_split<1,0><<<(TT*BB/128)*(H/128), 256, 0, stream>>>(
      wch, wcl, h1h + BH, h1l + BH, H, woutH, woutL,
      outY, nullptr, nullptr, TT*BB, H, 2*H, H/128);
}

// Round 21
// 1361.605 us; speedup vs baseline: 2.0887x; 1.0004x over previous
//
#include <hip/hip_runtime.h>
#include <hip/hip_bf16.h>
#include <stdint.h>

// Decoder: 2-layer LSTM + Luong attention. input_feed=0 => attention deferred
// post-loop. R21 = R20 (weights in LDS, 16 waves, hi-only h recurrence,
// counted-vmcnt double-buffered staging, sc0sc1 h stores, hierarchical
// barrier) + cells split across thread halves: tid<512 layer-0, tid>=512
// layer-1 (was: tid<512 doing both serially). Halves the cell VALU tail.

typedef __bf16 bf16_t;
typedef __bf16 bf16x8 __attribute__((ext_vector_type(8)));
typedef __bf16 bf16x4 __attribute__((ext_vector_type(4)));
typedef float f32x4 __attribute__((ext_vector_type(4)));

#define AS1 __attribute__((address_space(1)))
#define AS3 __attribute__((address_space(3)))

__device__ __forceinline__ void gll16(const bf16_t* g, bf16_t* l) {
  __builtin_amdgcn_global_load_lds((const AS1 void*)g, (AS3 void*)l, 16, 0, 0);
}

__device__ __forceinline__ float sigm(float x){ return 1.f/(1.f+expf(-x)); }

#define MFMA16(acc, a, b) acc = __builtin_amdgcn_mfma_f32_16x16x32_bf16(a, b, acc, 0,0,0)

// system write-through coherent store (proven R5..R20)
__device__ __forceinline__ void stg_sc(bf16_t* p, bf16_t v){
  uint32_t w = (uint32_t)__builtin_bit_cast(uint16_t, v);
  asm volatile("global_store_short %0, %1, off sc0 sc1" :: "v"(p), "v"(w) : "memory");
}

// ---------------- prep kernels ----------------
__global__ void f2b(const float* __restrict__ in, bf16_t* __restrict__ outp, int n){
  int i = (blockIdx.x*256 + threadIdx.x)*4;
  if (i >= n) return;
  float4 v = *(const float4*)(in + i);
  bf16x4 o; o[0]=(bf16_t)v.x; o[1]=(bf16_t)v.y; o[2]=(bf16_t)v.z; o[3]=(bf16_t)v.w;
  *(bf16x4*)(outp + i) = o;
}

__global__ void f2b_pair(const float* __restrict__ in, bf16_t* __restrict__ oh,
                         bf16_t* __restrict__ ol, int n){
  int i = (blockIdx.x*256 + threadIdx.x)*4;
  if (i >= n) return;
  float4 v = *(const float4*)(in + i);
  float vv[4] = {v.x, v.y, v.z, v.w};
  bf16x4 h, l;
  #pragma unroll
  for (int j=0;j<4;j++){ h[j]=(bf16_t)vv[j]; l[j]=(bf16_t)(vv[j]-(float)h[j]); }
  *(bf16x4*)(oh + i) = h;
  *(bf16x4*)(ol + i) = l;
}

__global__ void bias_combine(const float* __restrict__ a, const float* __restrict__ b,
                             float* __restrict__ o, int n){
  int i = blockIdx.x*256 + threadIdx.x;
  if (i < n) o[i] = a[i] + b[i];
}

__global__ void embed_gather(const int* __restrict__ tokp, const float* __restrict__ embW,
                             bf16_t* __restrict__ xe){
  int m = blockIdx.x;
  int tokv = tokp[m];
  const float* src = embW + (size_t)tokv*1024 + threadIdx.x*4;
  float4 v = *(const float4*)src;
  bf16x4 o; o[0]=(bf16_t)v.x; o[1]=(bf16_t)v.y; o[2]=(bf16_t)v.z; o[3]=(bf16_t)v.w;
  *(bf16x4*)(xe + (size_t)m*1024 + threadIdx.x*4) = o;
}

// winT[e,d] = split(Win[d,e])
__global__ void transWin(const float* __restrict__ in, bf16_t* __restrict__ oh,
                         bf16_t* __restrict__ ol){
  __shared__ float t[32][33];
  int bi = blockIdx.x & 31, bj = blockIdx.x >> 5;
  int tx = threadIdx.x & 31, ty = threadIdx.x >> 5;  // 32 x 8
  #pragma unroll
  for (int i=0;i<4;i++){
    int d = bi*32 + ty + i*8, e = bj*32 + tx;
    t[ty+i*8][tx] = in[(size_t)d*1024 + e];
  }
  __syncthreads();
  #pragma unroll
  for (int i=0;i<4;i++){
    int e = bj*32 + ty + i*8, d = bi*32 + tx;
    float v = t[tx][ty+i*8];
    bf16_t h = (bf16_t)v;
    oh[(size_t)e*1024 + d] = h;
    ol[(size_t)e*1024 + d] = (bf16_t)(v - (float)h);
  }
}

// -------- x0g GEMM: x0gT[t][bg][g][col][16 rows] = xemb@wih0^T + bias0 --------
__global__ __launch_bounds__(256) void gemm_bt(
    const bf16_t* __restrict__ A, const bf16_t* __restrict__ Bm,
    const float* __restrict__ bias, bf16_t* __restrict__ Cout,
    int M, int N, int K, int nTN)
{
  __shared__ bf16_t sA[128*64];
  __shared__ bf16_t sB[128*64];
  int tid = threadIdx.x, lane = tid & 63, w = tid >> 6;
  int tm = blockIdx.x / nTN, tn = blockIdx.x % nTN;
  int row0 = tm*128, col0 = tn*128;
  int wr = w >> 1, wcc = w & 1;
  f32x4 acc[4][4] = {};
  for (int kt = 0; kt < K; kt += 64) {
    __syncthreads();
    #pragma unroll
    for (int i=0;i<4;i++){
      int c = i*256 + tid;
      int r = c >> 3, kk = (c & 7) << 3;
      gll16(A  + (size_t)(row0+r)*K + kt + kk, sA + (size_t)(i*256 + w*64)*8);
      gll16(Bm + (size_t)(col0+r)*K + kt + kk, sB + (size_t)(i*256 + w*64)*8);
    }
    __syncthreads();
    #pragma unroll
    for (int kk=0;kk<64;kk+=32){
      bf16x8 av[4], bv[4];
      #pragma unroll
      for (int m=0;m<4;m++) av[m] = *(const bf16x8*)(sA + (wr*64 + m*16 + (lane&15))*64 + kk + ((lane>>4)<<3));
      #pragma unroll
      for (int n=0;n<4;n++) bv[n] = *(const bf16x8*)(sB + (wcc*64 + n*16 + (lane&15))*64 + kk + ((lane>>4)<<3));
      #pragma unroll
      for (int m=0;m<4;m++)
        #pragma unroll
        for (int n=0;n<4;n++)
          acc[m][n] = __builtin_amdgcn_mfma_f32_16x16x32_bf16(av[m], bv[n], acc[m][n], 0,0,0);
    }
  }
  #pragma unroll
  for (int n=0;n<4;n++){
    int cn = col0 + wcc*64 + n*16 + (lane & 15);
    float bvv = bias[cn];
    int g = cn >> 10, col = cn & 1023;
    #pragma unroll
    for (int m=0;m<4;m++){
      int rm = row0 + wr*64 + m*16 + ((lane>>4)<<2);
      int p = rm >> 7, bgi = (rm >> 4) & 7, rr = rm & 15;
      bf16x4 o;
      #pragma unroll
      for (int r=0;r<4;r++) o[r] = (bf16_t)(acc[m][n][r] + bvv);
      *(bf16x4*)(Cout + ((((size_t)p*8+bgi)*4+g)*1024 + col)*16 + rr) = o;
    }
  }
}

// ---------------- split GEMM: hi/lo A (two K-parts) x hi/lo B, 3 combos ----------------
template<int ACT_TANH, int OUT_PAIR>
__global__ __launch_bounds__(256) void gemm_split(
    const bf16_t* __restrict__ Ah1, const bf16_t* __restrict__ Al1,
    const bf16_t* __restrict__ Ah2, const bf16_t* __restrict__ Al2, int K1,
    const bf16_t* __restrict__ Bh, const bf16_t* __restrict__ Bl,
    float* __restrict__ Cf, bf16_t* __restrict__ Ch, bf16_t* __restrict__ Cl,
    int M, int N, int K, int nTN)
{
  __shared__ bf16_t sAh[128*64], sAl[128*64], sBh[128*64], sBl[128*64];
  int tid = threadIdx.x, lane = tid & 63, w = tid >> 6;
  int tm = blockIdx.x / nTN, tn = blockIdx.x % nTN;
  int row0 = tm*128, col0 = tn*128;
  int wr = w >> 1, wcc = w & 1;
  f32x4 acc[4][4] = {};
  for (int kt = 0; kt < K; kt += 64) {
    const bf16_t *Ah, *Al; int kl;
    if (kt < K1){ Ah=Ah1; Al=Al1; kl=kt; } else { Ah=Ah2; Al=Al2; kl=kt-K1; }
    __syncthreads();
    #pragma unroll
    for (int i=0;i<4;i++){
      int c = i*256 + tid;
      int r = c >> 3, kk = (c & 7) << 3;
      gll16(Ah + (size_t)(row0+r)*K1 + kl + kk, sAh + (size_t)(i*256 + w*64)*8);
      gll16(Al + (size_t)(row0+r)*K1 + kl + kk, sAl + (size_t)(i*256 + w*64)*8);
      gll16(Bh + (size_t)(col0+r)*K + kt + kk, sBh + (size_t)(i*256 + w*64)*8);
      gll16(Bl + (size_t)(col0+r)*K + kt + kk, sBl + (size_t)(i*256 + w*64)*8);
    }
    __syncthreads();
    #pragma unroll
    for (int kk=0;kk<64;kk+=32){
      bf16x8 avh[4], avl[4], bvh[4], bvl[4];
      #pragma unroll
      for (int m=0;m<4;m++){
        int off = (wr*64 + m*16 + (lane&15))*64 + kk + ((lane>>4)<<3);
        avh[m] = *(const bf16x8*)(sAh + off);
        avl[m] = *(const bf16x8*)(sAl + off);
      }
      #pragma unroll
      for (int n=0;n<4;n++){
        int off = (wcc*64 + n*16 + (lane&15))*64 + kk + ((lane>>4)<<3);
        bvh[n] = *(const bf16x8*)(sBh + off);
        bvl[n] = *(const bf16x8*)(sBl + off);
      }
      #pragma unroll
      for (int m=0;m<4;m++)
        #pragma unroll
        for (int n=0;n<4;n++){
          acc[m][n] = __builtin_amdgcn_mfma_f32_16x16x32_bf16(avh[m], bvh[n], acc[m][n], 0,0,0);
          acc[m][n] = __builtin_amdgcn_mfma_f32_16x16x32_bf16(avl[m], bvh[n], acc[m][n], 0,0,0);
          acc[m][n] = __builtin_amdgcn_mfma_f32_16x16x32_bf16(avh[m], bvl[n], acc[m][n], 0,0,0);
        }
    }
  }
  #pragma unroll
  for (int n=0;n<4;n++){
    int cn = col0 + wcc*64 + n*16 + (lane & 15);
    #pragma unroll
    for (int m=0;m<4;m++){
      int rm = row0 + wr*64 + m*16 + ((lane>>4)<<2);
      #pragma unroll
      for (int r=0;r<4;r++){
        float v = acc[m][n][r];
        if (ACT_TANH) v = tanhf(v);
        if (OUT_PAIR){
          bf16_t h = (bf16_t)v;
          Ch[(size_t)(rm+r)*N + cn] = h;
          Cl[(size_t)(rm+r)*N + cn] = (bf16_t)(v - (float)h);
        } else {
          Cf[(size_t)(rm+r)*N + cn] = v;
        }
      }
    }
  }
}

// ---------------- persistent LSTM loop: hi-only, counted dbuf, split cells ----------------
// 256 blocks x 1024 thr (16 waves = 8 row-groups rg x 2 K-halves kh).
#define NBLK 256
#define STGOFF 98304                  // 48*1024*2 bytes of weights
#define LDS_BYTES 163840              // + 16 waves * 2 x 2KB staging (sG aliased)

__global__ __launch_bounds__(1024, 4) void lstm_loop(
    const bf16_t* __restrict__ whh0, const bf16_t* __restrict__ wih1,
    const bf16_t* __restrict__ whh1, const bf16_t* __restrict__ x0gT,
    const float* __restrict__ bias1, const float* __restrict__ c0in,
    bf16_t* __restrict__ h0h,                                // hist [65][128][1024]
    bf16_t* __restrict__ h1h, bf16_t* __restrict__ h1l,      // hist [65][128][1024]
    float* __restrict__ outH, float* __restrict__ outC, int* bar, int* done)
{
  extern __shared__ char smem[];
  bf16_t* wlds = (bf16_t*)smem;
  float*  sG   = (float*)(smem + STGOFF);    // 4 regions x [128][17] (aliases staging)

  // one-time acquire: invalidate stale L1/L2 lines (poison / prior replay)
  __threadfence();

  const int tid = threadIdx.x, lane = tid & 63, wv = tid >> 6;
  const int l15 = lane & 15, hi4 = lane >> 4;
  const int hc0 = blockIdx.x * 4;
  const int rg = wv & 7, kh = wv >> 3;

  // ---- stage weights into LDS once (XOR slot swizzle: slot ^ (row&7)) ----
  for (int e = tid; e < 6144; e += 1024){
    int m = e >> 11, r = e & 2047, n = r >> 7, kc = r & 127;
    const bf16_t* Wm = (m == 0) ? whh0 : ((m == 1) ? wih1 : whh1);
    int row = ((n >> 2) << 10) + hc0 + (n & 3);
    bf16x8 v = *(const bf16x8*)(Wm + (size_t)row*1024 + kc*8);
    *(bf16x8*)(wlds + (size_t)(m*16 + n)*1024 + (kc ^ (n & 7))*8) = v;
  }
  __syncthreads();

  // cell mapping: tid<512 -> layer-0 cell; tid>=512 -> layer-1 cell
  const bool cell0 = (tid < 512);
  const int t2 = cell0 ? tid : (tid - 512);
  const int crow = t2 >> 2, q = t2 & 3;
  const size_t cellix = (size_t)crow*1024 + hc0 + q;
  float c0reg = 0.f, c1reg = 0.f, bs[4] = {};
  if (cell0){
    c0reg = c0in[cellix];
  } else {
    c1reg = c0in[131072 + cellix];
    #pragma unroll
    for (int g=0; g<4; ++g) bs[g] = bias1[(g<<10) + hc0 + q];
  }

  // staging: 2 rotating buffers of 2KB (2 arrays x 512 elems) per wave
  bf16_t* mybuf = (bf16_t*)(smem + STGOFF + wv*4096);
  const size_t srcoff = (size_t)(rg*16 + (lane >> 2))*1024
                      + (size_t)(((lane & 3) ^ ((lane >> 4) & 3)) * 8);
  const int rdoff = l15*32 + ((hi4 ^ ((l15 >> 2) & 3)) * 8);
  const int wbA = (0*16 + l15)*1024;
  const int wbB = (1*16 + l15)*1024;
  const int wbC = (2*16 + l15)*1024;

  for (int p = 0; p <= 64; ++p){
    const bf16_t* h0h_ = h0h + (size_t)p*131072;
    const bf16_t* h1ph = h1h + (size_t)(p >= 1 ? p-1 : 0)*131072;

    // x0g loads (dense transposed layout); drained by first counted wait
    float xg[4] = {0,0,0,0};
    if (cell0 && p < 64){
      int bg = crow >> 4, rr = crow & 15;
      #pragma unroll
      for (int g=0; g<4; ++g)
        xg[g] = (float)x0gT[((((size_t)p*8 + bg)*4 + g)*1024 + hc0 + q)*16 + rr];
    }

    // ---- K-loop: depth-1 counted-vmcnt double-buffered pipeline ----
    f32x4 accA = {}, accB = {};
    {
      // prologue: batch 0 into buffer 0
      gll16(h0h_ + srcoff + kh*512, mybuf + 0);
      gll16(h1ph + srcoff + kh*512, mybuf + 512);
      #pragma unroll
      for (int c = 0; c < 16; ++c){
        const int cur = (c & 1) * 1024;
        if (c < 15){
          const int alt = ((c+1) & 1) * 1024;
          const int k1 = kh*512 + (c+1)*32;
          gll16(h0h_ + srcoff + k1, mybuf + alt);
          gll16(h1ph + srcoff + k1, mybuf + alt + 512);
          asm volatile("s_waitcnt vmcnt(2)" ::: "memory");  // batch c landed
        } else {
          asm volatile("s_waitcnt vmcnt(0)" ::: "memory");
        }
        __builtin_amdgcn_sched_barrier(0);
        bf16x8 a0 = *(const bf16x8*)(mybuf + cur + rdoff);
        bf16x8 a1 = *(const bf16x8*)(mybuf + cur + 512 + rdoff);
        asm volatile("s_waitcnt lgkmcnt(0)" ::: "memory");  // frags in VGPR; buffer reusable
        __builtin_amdgcn_sched_barrier(0);
        const int slot = kh*64 + c*4 + hi4;
        const int ws = (slot ^ (l15 & 7)) * 8;
        bf16x8 w0 = *(const bf16x8*)(wlds + wbA + ws);
        bf16x8 w1 = *(const bf16x8*)(wlds + wbB + ws);
        bf16x8 w2 = *(const bf16x8*)(wlds + wbC + ws);
        MFMA16(accA, a0, w0);
        MFMA16(accB, a0, w1);
        MFMA16(accB, a1, w2);
      }
    }

    // ---- staging dead; sG (aliased) becomes live ----
    __syncthreads();
    {
      const int rowb = rg*16 + hi4*4;
      #pragma unroll
      for (int r=0;r<4;r++){
        sG[(0*2 + kh)*2176 + (rowb + r)*17 + l15] = accA[r];
        sG[(2 + kh)*2176 + (rowb + r)*17 + l15]   = accB[r];
      }
    }
    __syncthreads();

    // ---- cells: layer-0 on tid<512, layer-1 on tid>=512 (parallel) ----
    if (cell0){
      if (p < 64){
        float gv[4];
        #pragma unroll
        for (int g=0; g<4; ++g)
          gv[g] = sG[0*2176 + crow*17 + g*4 + q] + sG[1*2176 + crow*17 + g*4 + q] + xg[g];
        float cv = sigm(gv[1])*c0reg + sigm(gv[0])*tanhf(gv[2]);
        float hv = sigm(gv[3])*tanhf(cv);
        c0reg = cv;
        stg_sc(h0h + (size_t)(p+1)*131072 + cellix, (bf16_t)hv);
        if (p == 63){ outH[cellix] = hv; outC[cellix] = cv; }
      }
    } else {
      if (p >= 1){
        float gv[4];
        #pragma unroll
        for (int g=0; g<4; ++g)
          gv[g] = sG[2*2176 + crow*17 + g*4 + q] + sG[3*2176 + crow*17 + g*4 + q] + bs[g];
        float cv = sigm(gv[1])*c1reg + sigm(gv[0])*tanhf(gv[2]);
        float hv = sigm(gv[3])*tanhf(cv);
        c1reg = cv;
        bf16_t hh = (bf16_t)hv;
        stg_sc(h1h + (size_t)p*131072 + cellix, hh);
        stg_sc(h1l + (size_t)p*131072 + cellix, (bf16_t)(hv - (float)hh));
        if (p == 64){ outH[131072 + cellix] = hv; outC[131072 + cellix] = cv; }
      }
    }

    // ---- hierarchical grid barrier: spread signal, single-flag poll ----
    if (p < 64){
      __syncthreads();   // drains each wave's vmem (incl. sc stores)
      if (tid == 0){
        __hip_atomic_fetch_add(bar + (blockIdx.x & 15)*64, 1, __ATOMIC_RELAXED, __HIP_MEMORY_SCOPE_AGENT);
        if (blockIdx.x == 0){
          const int tgt = NBLK*(p+1);
          for(;;){
            int s = 0;
            #pragma unroll
            for (int i=0;i<16;i++)
              s += __hip_atomic_load(bar + i*64, __ATOMIC_RELAXED, __HIP_MEMORY_SCOPE_AGENT);
            if (s >= tgt) break;
            __builtin_amdgcn_s_sleep(1);
          }
          __hip_atomic_store(done, p+1, __ATOMIC_RELAXED, __HIP_MEMORY_SCOPE_AGENT);
        } else {
          while (__hip_atomic_load(done, __ATOMIC_RELAXED, __HIP_MEMORY_SCOPE_AGENT) < p+1)
            __builtin_amdgcn_s_sleep(1);
        }
      }
      __syncthreads();
      asm volatile("" ::: "memory");
      __builtin_amdgcn_sched_barrier(0);
    }
  }
}

// ---------------- scores + softmax (per batch row b), post-loop ----------------
__global__ __launch_bounds__(256) void attn_sm(
    const bf16_t* __restrict__ h1h, const bf16_t* __restrict__ h1l,
    const bf16_t* __restrict__ cwh, const bf16_t* __restrict__ cwl,
    float* __restrict__ a_all, float* __restrict__ outA)
{
  __shared__ bf16_t sAh[64*64], sAl[64*64];
  __shared__ bf16_t sBh[128*64], sBl[128*64];
  __shared__ float sS[64*128];
  int b = blockIdx.x;
  int tid = threadIdx.x, lane = tid&63, w = tid>>6;
  int wr = w>>1, wcc = w&1;
  f32x4 acc[2][4] = {};
  for (int kt=0; kt<1024; kt+=64){
    __syncthreads();
    #pragma unroll
    for (int i=0;i<2;i++){
      int c = i*256+tid; int r = c>>3, kk=(c&7)<<3;
      size_t src = (size_t)(r+1)*131072 + (size_t)b*1024 + kt+kk;
      gll16(h1h + src, sAh + (size_t)(i*256 + w*64)*8);
      gll16(h1l + src, sAl + (size_t)(i*256 + w*64)*8);
    }
    #pragma unroll
    for (int i=0;i<4;i++){
      int c = i*256+tid; int br=c>>3, kk=(c&7)<<3;
      size_t src = ((size_t)b*128 + br)*1024 + kt+kk;
      gll16(cwh + src, sBh + (size_t)(i*256+w*64)*8);
      gll16(cwl + src, sBl + (size_t)(i*256+w*64)*8);
    }
    __syncthreads();
    #pragma unroll
    for (int kk=0;kk<64;kk+=32){
      bf16x8 avh[2], avl[2], bvh[4], bvl[4];
      #pragma unroll
      for (int m=0;m<2;m++){
        int off = (wr*32 + m*16 + (lane&15))*64 + kk + ((lane>>4)<<3);
        avh[m] = *(const bf16x8*)(sAh + off);
        avl[m] = *(const bf16x8*)(sAl + off);
      }
      #pragma unroll
      for (int n=0;n<4;n++){
        int off = (wcc*64 + n*16 + (lane&15))*64 + kk + ((lane>>4)<<3);
        bvh[n] = *(const bf16x8*)(sBh + off);
        bvl[n] = *(const bf16x8*)(sBl + off);
      }
      #pragma unroll
      for (int m=0;m<2;m++)
        #pragma unroll
        for (int n=0;n<4;n++){
          acc[m][n] = __builtin_amdgcn_mfma_f32_16x16x32_bf16(avh[m], bvh[n], acc[m][n], 0,0,0);
          acc[m][n] = __builtin_amdgcn_mfma_f32_16x16x32_bf16(avl[m], bvh[n], acc[m][n], 0,0,0);
          acc[m][n] = __builtin_amdgcn_mfma_f32_16x16x32_bf16(avh[m], bvl[n], acc[m][n], 0,0,0);
        }
    }
  }
  #pragma unroll
  for (int m=0;m<2;m++)
    #pragma unroll
    for (int n=0;n<4;n++)
      #pragma unroll
      for (int r=0;r<4;r++){
        int trow = wr*32 + m*16 + ((lane>>4)<<2) + r;
        int tc   = wcc*64 + n*16 + (lane&15);
        sS[trow*128+tc] = acc[m][n][r];
      }
  __syncthreads();
  for (int i=0;i<16;i++){
    int r = w*16 + i;
    float v0 = sS[r*128 + lane], v1 = sS[r*128 + 64 + lane];
    float mx = fmaxf(v0, v1);
    #pragma unroll
    for (int off=32; off; off>>=1) mx = fmaxf(mx, __shfl_xor(mx, off));
    float e0 = expf(v0-mx), e1 = expf(v1-mx);
    float sm = e0+e1;
    #pragma unroll
    for (int off=32; off; off>>=1) sm += __shfl_xor(sm, off);
    float inv = 1.f/sm;
    size_t base = ((size_t)r*128 + b)*128;
    a_all[base + lane]      = e0*inv;
    a_all[base + 64 + lane] = e1*inv;
    if (r == 63){
      outA[(size_t)b*128 + lane]      = e0*inv;
      outA[(size_t)b*128 + 64 + lane] = e1*inv;
    }
  }
}

// ---------------- wc (fp32 VALU): wc[t,b,:] = sum_s a[t,b,s]*ctx[b,s,:] ----
__global__ __launch_bounds__(256) void wc_all(
    const float* __restrict__ a_all, const float* __restrict__ ctx,
    bf16_t* __restrict__ wch, bf16_t* __restrict__ wcl)
{
  int bid = blockIdx.x;
  int b = bid & 127, tg = bid >> 7;  // tg 0..3, 16 t each
  int tid = threadIdx.x;
  __shared__ float sa[16][128];
  int t0 = tg*16;
  #pragma unroll
  for (int i=0;i<8;i++){
    int q = i*256 + tid;
    int ti = q >> 7, s = q & 127;
    sa[ti][s] = a_all[((size_t)(t0+ti)*128 + b)*128 + s];
  }
  __syncthreads();
  f32x4 acc[16];
  #pragma unroll
  for (int i=0;i<16;i++) acc[i] = f32x4{0,0,0,0};
  const float* cb = ctx + (size_t)b*128*1024 + tid*4;
  for (int s=0;s<128;s++){
    f32x4 c = *(const f32x4*)(cb + (size_t)s*1024);
    #pragma unroll
    for (int ti=0;ti<16;ti++){
      float av = sa[ti][s];
      acc[ti] += av * c;
    }
  }
  #pragma unroll
  for (int ti=0;ti<16;ti++){
    size_t m = (size_t)(t0+ti)*128 + b;
    bf16x4 h, l;
    #pragma unroll
    for (int j=0;j<4;j++){
      float v = acc[ti][j];
      h[j] = (bf16_t)v; l[j] = (bf16_t)(v - (float)h[j]);
    }
    *(bf16x4*)(wch + m*1024 + tid*4) = h;
    *(bf16x4*)(wcl + m*1024 + tid*4) = l;
  }
}

// ---------------- host ----------------
extern "C" void kernel_launch(void* const* d_in, const int* in_sizes, int n_in,
                              void* d_out, int out_size, void* d_ws, size_t ws_size,
                              hipStream_t stream)
{
  (void)in_sizes; (void)n_in; (void)out_size; (void)ws_size;
  const int TT=64, BB=128, H=1024, G=4096, BH=128*1024;

  const int*   tok  = (const int*)d_in[0];
  const float* h0   = (const float*)d_in[1];
  const float* c0   = (const float*)d_in[2];
  const float* ctx  = (const float*)d_in[3];
  const float* embW = (const float*)d_in[5];
  const float* wih  = (const float*)d_in[6];
  const float* whh  = (const float*)d_in[7];
  const float* bih  = (const float*)d_in[8];
  const float* bhh  = (const float*)d_in[9];
  const float* Win  = (const float*)d_in[10];
  const float* Wout = (const float*)d_in[11];

  float* outY = (float*)d_out;                      // [T,B,H]
  float* outH = outY + (size_t)TT*BB*H;             // [2,B,H]
  float* outC = outH + (size_t)2*BH;                // [2,B,H]
  float* outA = outC + (size_t)2*BH;                // [B,S]

  char* ws = (char*)d_ws;
  size_t o = 0;
  auto carve = [&](size_t bytes)->char* {
    char* p = ws + o; o += (bytes + 255) & ~(size_t)255; return p;
  };
  bf16_t* wihB  = (bf16_t*)carve((size_t)2*G*H*2);       // 16MB
  bf16_t* whhB  = (bf16_t*)carve((size_t)2*G*H*2);       // 16MB
  bf16_t* woutH = (bf16_t*)carve((size_t)H*2*H*2);       // 4MB
  bf16_t* woutL = (bf16_t*)carve((size_t)H*2*H*2);       // 4MB
  bf16_t* winTh = (bf16_t*)carve((size_t)H*H*2);         // 2MB
  bf16_t* winTl = (bf16_t*)carve((size_t)H*H*2);         // 2MB
  bf16_t* ctxh  = (bf16_t*)carve((size_t)BB*128*H*2);    // 32MB; loop: h0 hist; post: wch
  bf16_t* ctxl  = (bf16_t*)carve((size_t)BB*128*H*2);    // 32MB; post: wcl
  bf16_t* cwh   = (bf16_t*)carve((size_t)BB*128*H*2);    // 32MB (pre: xemb overlays)
  bf16_t* cwl   = (bf16_t*)carve((size_t)BB*128*H*2);    // 32MB
  bf16_t* x0gT  = (bf16_t*)carve((size_t)TT*BB*G*2);     // 64MB
  bf16_t* h1h   = (bf16_t*)carve((size_t)(TT+1)*BH*2);   // 17MB history
  bf16_t* h1l   = (bf16_t*)carve((size_t)(TT+1)*BH*2);   // 17MB
  float*  a_all = (float*)carve((size_t)TT*BB*128*4);    // 4MB
  float*  biasF = (float*)carve((size_t)2*G*4);
  int*    bar   = (int*)carve(16*64*4);
  int*    done  = (int*)carve(256);

  bf16_t* xemb   = cwh;          // overlays ctxW-hi (dead until ctxW GEMM)
  bf16_t* h0hist = ctxh;         // h0 history [65][128][1024] (ctx dead after ctxW GEMM)
  bf16_t* wch    = ctxh;         // post-loop overlay (h0 hist dead then)
  bf16_t* wcl    = ctxl;

  // ---- prep ----
  hipMemsetAsync(bar, 0, 16*64*4, stream);
  hipMemsetAsync(done, 0, 256, stream);
  f2b<<<(2*G*H)/1024, 256, 0, stream>>>(wih, wihB, 2*G*H);
  f2b<<<(2*G*H)/1024, 256, 0, stream>>>(whh, whhB, 2*G*H);
  f2b_pair<<<(H*2*H)/1024, 256, 0, stream>>>(Wout, woutH, woutL, H*2*H);
  f2b_pair<<<(BB*128*H)/1024, 256, 0, stream>>>(ctx, ctxh, ctxl, BB*128*H);
  f2b_pair<<<BH/1024, 256, 0, stream>>>(h0 + BH, h1h, h1l, BH);
  transWin<<<1024, 256, 0, stream>>>(Win, winTh, winTl);
  bias_combine<<<(2*G)/256, 256, 0, stream>>>(bih, bhh, biasF, 2*G);
  embed_gather<<<TT*BB, 256, 0, stream>>>(tok, embW, xemb);

  // ---- one-time GEMMs ----
  gemm_bt<<<(TT*BB/128)*(G/128), 256, 0, stream>>>(xemb, wihB, biasF, x0gT, TT*BB, G, H, G/128);
  gemm_split<0,1><<<(BB*128/128)*(H/128), 256, 0, stream>>>(
      ctxh, ctxl, ctxh, ctxl, H, winTh, winTl,
      nullptr, cwh, cwl, BB*128, H, H, H/128);

  // h0 layer-0 initial state (hi only) -> h0 history slot 0 (ctx region now dead)
  f2b<<<BH/1024, 256, 0, stream>>>(h0, h0hist, BH);

  // ---- persistent recurrence ----
  hipFuncSetAttribute((const void*)lstm_loop,
                      hipFuncAttributeMaxDynamicSharedMemorySize, LDS_BYTES);
  lstm_loop<<<NBLK, 1024, LDS_BYTES, stream>>>(
      whhB, wihB + (size_t)G*H, whhB + (size_t)G*H, x0gT, biasF + G, c0,
      h0hist, h1h, h1l, outH, outC, bar, done);

  // ---- post-loop attention ----
  attn_sm<<<BB, 256, 0, stream>>>(h1h, h1l, cwh, cwl, a_all, outA);
  wc_all<<<BB*4, 256, 0, stream>>>(a_all, ctx, wch, wcl);

  gemm_split<1,0><<<(TT*BB/128)*(H/128), 256, 0, stream>>>(
      wch, wcl, h1h + BH, h1l + BH, H, woutH, woutL,
      outY, nullptr, nullptr, TT*BB, H, 2*H, H/128);
}